// Round 2
// baseline (537.252 us; speedup 1.0000x reference)
//
#include <hip/hip_runtime.h>
#include <stdint.h>

typedef __bf16 bf16x8 __attribute__((ext_vector_type(8)));
typedef float f32x4 __attribute__((ext_vector_type(4)));

__device__ __forceinline__ ushort f2bf(float f) {
  uint32_t u = __float_as_uint(f);
  u += 0x7FFFu + ((u >> 16) & 1u);
  return (ushort)(u >> 16);
}
__device__ __forceinline__ float bf2f(ushort u) {
  return __uint_as_float(((uint32_t)u) << 16);
}

// ---------------- cast f32 -> bf16, 8 elems/thread ----------------
__global__ __launch_bounds__(256) void k_cast_bf16(const float* __restrict__ in,
                                                   ushort* __restrict__ out, long n) {
  long i = ((long)blockIdx.x * 256 + threadIdx.x) * 8;
  if (i >= n) return;
  float4 a = *(const float4*)(in + i);
  float4 b = *(const float4*)(in + i + 4);
  uint4 r;
  r.x = (uint)f2bf(a.x) | ((uint)f2bf(a.y) << 16);
  r.y = (uint)f2bf(a.z) | ((uint)f2bf(a.w) << 16);
  r.z = (uint)f2bf(b.x) | ((uint)f2bf(b.y) << 16);
  r.w = (uint)f2bf(b.z) | ((uint)f2bf(b.w) << 16);
  *(uint4*)(out + i) = r;
}

// ---------------- W [K=256, N=256] f32 -> Wt [N,K] bf16 ----------------
__global__ void k_transpose_w(const float* __restrict__ W, ushort* __restrict__ Wt) {
  int n = blockIdx.x;      // output row (N dim)
  int k = threadIdx.x;     // 0..255
  Wt[n * 256 + k] = f2bf(W[k * 256 + n]);
}

// ---------------- CSR build ----------------
__global__ __launch_bounds__(256) void k_count(const int* __restrict__ dst, int* __restrict__ cnt, int E) {
  int i = blockIdx.x * 256 + threadIdx.x;
  if (i < E) atomicAdd(&cnt[dst[i]], 1);
}

__global__ __launch_bounds__(1024) void k_exscan(const int* __restrict__ cnt,
                                                 int* __restrict__ rowptr, int N) {
  __shared__ int wsum[16];
  __shared__ int carry;
  int tid = threadIdx.x, lane = tid & 63, wv = tid >> 6;
  if (tid == 0) { carry = 0; rowptr[0] = 0; }
  __syncthreads();
  for (int base = 0; base < N; base += 1024) {
    int i = base + tid;
    int v = (i < N) ? cnt[i] : 0;
    int x = v;
#pragma unroll
    for (int off = 1; off < 64; off <<= 1) {
      int y = __shfl_up(x, off);
      if (lane >= off) x += y;
    }
    if (lane == 63) wsum[wv] = x;
    __syncthreads();
    if (wv == 0) {
      int s = (lane < 16) ? wsum[lane] : 0;
#pragma unroll
      for (int off = 1; off < 16; off <<= 1) {
        int y = __shfl_up(s, off);
        if (lane >= off) s += y;
      }
      if (lane < 16) wsum[lane] = s;
    }
    __syncthreads();
    int woff = wv ? wsum[wv - 1] : 0;
    int total = wsum[15];
    int c = carry;
    if (i < N) rowptr[i + 1] = c + woff + x;
    __syncthreads();
    if (tid == 0) carry = c + total;
    __syncthreads();
  }
}

__global__ __launch_bounds__(256) void k_scatter(const int* __restrict__ dst,
                                                 const int* __restrict__ rowptr,
                                                 int* __restrict__ fill,
                                                 int* __restrict__ eidx, int E) {
  int e = blockIdx.x * 256 + threadIdx.x;
  if (e < E) {
    int d = dst[e];
    int p = atomicAdd(&fill[d], 1);
    eidx[rowptr[d] + p] = e;
  }
}

// ------- bf16 MFMA GEMM: C_f32[M,256] = A_bf16[M,256] @ Wt_bf16^T (Wt is [N,K]) -------
#define BM 128
#define BN 128
#define BK 64
#define LDK 72  // padded LDS row (bf16 elems)

__global__ __launch_bounds__(256) void k_gemm_bf16(const ushort* __restrict__ A,
                                                   const ushort* __restrict__ Bt,
                                                   float* __restrict__ C, int M) {
  __shared__ __align__(16) ushort As[BM * LDK];
  __shared__ __align__(16) ushort Bs[BN * LDK];
  const int K = 256, N = 256;
  int bm = blockIdx.x * BM;
  int bn = blockIdx.y * BN;
  int tid = threadIdx.x;
  int lane = tid & 63, wid = tid >> 6;
  int wr = wid >> 1, wc = wid & 1;  // wave 64x64 subtile

  f32x4 acc[4][4];
#pragma unroll
  for (int mi = 0; mi < 4; ++mi)
#pragma unroll
    for (int ni = 0; ni < 4; ++ni) acc[mi][ni] = (f32x4){0.f, 0.f, 0.f, 0.f};

  for (int kt = 0; kt < K; kt += BK) {
#pragma unroll
    for (int i = 0; i < 4; ++i) {  // A tile 128x64
      int flat = i * 2048 + tid * 8;
      int r = flat >> 6, c = flat & 63;
      int gr = bm + r;
      uint4 v = {0u, 0u, 0u, 0u};
      if (gr < M) v = *(const uint4*)(A + (size_t)gr * K + kt + c);
      *(uint4*)(As + r * LDK + c) = v;
    }
#pragma unroll
    for (int i = 0; i < 4; ++i) {  // B tile 128x64 (rows of Wt, N=256 always in-bounds)
      int flat = i * 2048 + tid * 8;
      int r = flat >> 6, c = flat & 63;
      uint4 v = *(const uint4*)(Bt + (size_t)(bn + r) * K + kt + c);
      *(uint4*)(Bs + r * LDK + c) = v;
    }
    __syncthreads();
#pragma unroll
    for (int s = 0; s < 2; ++s) {  // two K=32 slices
      bf16x8 af[4], bfr[4];
      int cc = s * 32 + (lane >> 4) * 8;
#pragma unroll
      for (int mi = 0; mi < 4; ++mi) {
        int r = wr * 64 + mi * 16 + (lane & 15);
        af[mi] = *(const bf16x8*)(As + r * LDK + cc);
      }
#pragma unroll
      for (int ni = 0; ni < 4; ++ni) {
        int r = wc * 64 + ni * 16 + (lane & 15);
        bfr[ni] = *(const bf16x8*)(Bs + r * LDK + cc);
      }
#pragma unroll
      for (int mi = 0; mi < 4; ++mi)
#pragma unroll
        for (int ni = 0; ni < 4; ++ni)
          acc[mi][ni] = __builtin_amdgcn_mfma_f32_16x16x32_bf16(af[mi], bfr[ni], acc[mi][ni], 0, 0, 0);
    }
    __syncthreads();
  }
  // C/D layout: col = lane&15, row = (lane>>4)*4 + reg
#pragma unroll
  for (int mi = 0; mi < 4; ++mi) {
#pragma unroll
    for (int j = 0; j < 4; ++j) {
      int gr = bm + wr * 64 + mi * 16 + (lane >> 4) * 4 + j;
      if (gr < M) {
#pragma unroll
        for (int ni = 0; ni < 4; ++ni) {
          int gc = bn + wc * 64 + ni * 16 + (lane & 15);
          C[(size_t)gr * N + gc] = acc[mi][ni][j];
        }
      }
    }
  }
}

// ---------------- el/er: one thread per (node, head) ----------------
__global__ __launch_bounds__(256) void k_eler(const float* __restrict__ feat,
                                              const float* __restrict__ al,
                                              const float* __restrict__ ar,
                                              float* __restrict__ el, float* __restrict__ er,
                                              int N) {
  int idx = blockIdx.x * 256 + threadIdx.x;
  if (idx >= N * 4) return;
  int n = idx >> 2, h = idx & 3;
  const float* f = feat + (size_t)n * 256 + h * 64;
  const float* alp = al + h * 64;
  const float* arp = ar + h * 64;
  float sl = 0.f, sr = 0.f;
#pragma unroll
  for (int d = 0; d < 64; d += 4) {
    float4 v = *(const float4*)(f + d);
    float4 a = *(const float4*)(alp + d);
    float4 b = *(const float4*)(arp + d);
    sl += v.x * a.x + v.y * a.y + v.z * a.z + v.w * a.w;
    sr += v.x * b.x + v.y * b.y + v.z * b.z + v.w * b.w;
  }
  el[idx] = sl;
  er[idx] = sr;
}

// ------- fused edge-softmax + aggregation: one wave per dst node, lane = dim -------
__global__ __launch_bounds__(256) void k_agg(const float* __restrict__ feat,
                                             const float* __restrict__ el,
                                             const float* __restrict__ er,
                                             const int* __restrict__ rowptr,
                                             const int* __restrict__ eidx,
                                             const int* __restrict__ src,
                                             const float* __restrict__ resid,
                                             float* __restrict__ out_f32,
                                             ushort* __restrict__ out_bf16, int N) {
  int wv = threadIdx.x >> 6;
  int lane = threadIdx.x & 63;
  int n = blockIdx.x * 4 + wv;
  if (n >= N) return;
  int e0 = rowptr[n], e1 = rowptr[n + 1];
  float4 ern = *(const float4*)(er + (size_t)n * 4);

  // phase 1: per-head max over incoming edges (lane-parallel over edges)
  float m0 = -1e30f, m1 = -1e30f, m2 = -1e30f, m3 = -1e30f;
  for (int j = e0 + lane; j < e1; j += 64) {
    int s = src[eidx[j]];
    float4 e = *(const float4*)(el + (size_t)s * 4);
    float v;
    v = e.x + ern.x; v = v >= 0.f ? v : 0.2f * v; m0 = fmaxf(m0, v);
    v = e.y + ern.y; v = v >= 0.f ? v : 0.2f * v; m1 = fmaxf(m1, v);
    v = e.z + ern.z; v = v >= 0.f ? v : 0.2f * v; m2 = fmaxf(m2, v);
    v = e.w + ern.w; v = v >= 0.f ? v : 0.2f * v; m3 = fmaxf(m3, v);
  }
#pragma unroll
  for (int off = 32; off >= 1; off >>= 1) {
    m0 = fmaxf(m0, __shfl_xor(m0, off));
    m1 = fmaxf(m1, __shfl_xor(m1, off));
    m2 = fmaxf(m2, __shfl_xor(m2, off));
    m3 = fmaxf(m3, __shfl_xor(m3, off));
  }

  // phase 2: accumulate exp(e-m)*feat[src] and denominator (lane l owns dim l of each head)
  float den0 = 0.f, den1 = 0.f, den2 = 0.f, den3 = 0.f;
  float a0 = 0.f, a1 = 0.f, a2 = 0.f, a3 = 0.f;
  for (int j = e0; j < e1; ++j) {
    int s = src[eidx[j]];
    float4 e = *(const float4*)(el + (size_t)s * 4);
    float v0 = e.x + ern.x; v0 = v0 >= 0.f ? v0 : 0.2f * v0;
    float v1 = e.y + ern.y; v1 = v1 >= 0.f ? v1 : 0.2f * v1;
    float v2 = e.z + ern.z; v2 = v2 >= 0.f ? v2 : 0.2f * v2;
    float v3 = e.w + ern.w; v3 = v3 >= 0.f ? v3 : 0.2f * v3;
    float w0 = __expf(v0 - m0), w1 = __expf(v1 - m1), w2 = __expf(v2 - m2), w3 = __expf(v3 - m3);
    den0 += w0; den1 += w1; den2 += w2; den3 += w3;
    const float* fr = feat + (size_t)s * 256;
    a0 += w0 * fr[lane];
    a1 += w1 * fr[64 + lane];
    a2 += w2 * fr[128 + lane];
    a3 += w3 * fr[192 + lane];
  }
  float o0 = a0 / fmaxf(den0, 1e-9f);
  float o1 = a1 / fmaxf(den1, 1e-9f);
  float o2 = a2 / fmaxf(den2, 1e-9f);
  float o3 = a3 / fmaxf(den3, 1e-9f);

  size_t base = (size_t)n * 256;
  if (resid) {
    o0 += resid[base + lane];
    o1 += resid[base + 64 + lane];
    o2 += resid[base + 128 + lane];
    o3 += resid[base + 192 + lane];
  }
  o0 = fmaxf(o0, 0.f); o1 = fmaxf(o1, 0.f); o2 = fmaxf(o2, 0.f); o3 = fmaxf(o3, 0.f);
  if (out_f32) {
    out_f32[base + lane] = o0;
    out_f32[base + 64 + lane] = o1;
    out_f32[base + 128 + lane] = o2;
    out_f32[base + 192 + lane] = o3;
  }
  if (out_bf16) {
    out_bf16[base + lane] = f2bf(o0);
    out_bf16[base + 64 + lane] = f2bf(o1);
    out_bf16[base + 128 + lane] = f2bf(o2);
    out_bf16[base + 192 + lane] = f2bf(o3);
  }
}

extern "C" void kernel_launch(void* const* d_in, const int* in_sizes, int n_in,
                              void* d_out, int out_size, void* d_ws, size_t ws_size,
                              hipStream_t stream) {
  const float* x = (const float*)d_in[0];
  const int* src = (const int*)d_in[1];
  const int* dst = (const int*)d_in[2];
  const float* W[3]  = {(const float*)d_in[3], (const float*)d_in[6], (const float*)d_in[9]};
  const float* al[3] = {(const float*)d_in[4], (const float*)d_in[7], (const float*)d_in[10]};
  const float* ar[3] = {(const float*)d_in[5], (const float*)d_in[8], (const float*)d_in[11]};
  const int N = in_sizes[0] / 256;
  const int E = in_sizes[1];
  float* out = (float*)d_out;

  char* ws = (char*)d_ws;
  size_t off = 0;
  auto alloc = [&](size_t bytes) -> void* {
    void* p = ws + off;
    off += (bytes + 255) & ~(size_t)255;
    return p;
  };
  ushort* xb    = (ushort*)alloc((size_t)N * 256 * 2);   // bf16 cast of x
  ushort* h1b   = (ushort*)alloc((size_t)N * 256 * 2);   // layer0 out, bf16 (GEMM input)
  ushort* h2b   = (ushort*)alloc((size_t)N * 256 * 2);   // layer1 out, bf16 (GEMM input)
  float*  featf = (float*)alloc((size_t)N * 256 * 4);    // GEMM output, f32
  float*  el    = (float*)alloc((size_t)N * 4 * 4);
  float*  er    = (float*)alloc((size_t)N * 4 * 4);
  ushort* Wt[3];
  for (int i = 0; i < 3; ++i) Wt[i] = (ushort*)alloc(256 * 256 * 2);
  int* cnt    = (int*)alloc((size_t)N * 4);
  int* rowptr = (int*)alloc((size_t)(N + 1) * 4);
  int* fill   = (int*)alloc((size_t)N * 4);
  int* eidx   = (int*)alloc((size_t)E * 4);
  // d_out doubles as the f32 h1 buffer (residual input for layer 1);
  // it is fully overwritten by layer 2's aggregation.

  long totx = (long)N * 256;
  k_cast_bf16<<<(int)((totx / 8 + 255) / 256), 256, 0, stream>>>(x, xb, totx);
  for (int i = 0; i < 3; ++i) k_transpose_w<<<256, 256, 0, stream>>>(W[i], Wt[i]);
  hipMemsetAsync(cnt, 0, (size_t)N * 4, stream);
  hipMemsetAsync(fill, 0, (size_t)N * 4, stream);
  k_count<<<(E + 255) / 256, 256, 0, stream>>>(dst, cnt, E);
  k_exscan<<<1, 1024, 0, stream>>>(cnt, rowptr, N);
  k_scatter<<<(E + 255) / 256, 256, 0, stream>>>(dst, rowptr, fill, eidx, E);

  dim3 ggrid((N + BM - 1) / BM, 2);
  dim3 agrid((N + 3) / 4);
  int egrid = (N * 4 + 255) / 256;

  // layer 0: residual = x (f32); outputs: d_out (f32 h1) + h1b (bf16)
  k_gemm_bf16<<<ggrid, 256, 0, stream>>>(xb, Wt[0], featf, N);
  k_eler<<<egrid, 256, 0, stream>>>(featf, al[0], ar[0], el, er, N);
  k_agg<<<agrid, 256, 0, stream>>>(featf, el, er, rowptr, eidx, src, x, out, h1b, N);

  // layer 1: residual = d_out (f32 h1); output: h2b (bf16 only)
  k_gemm_bf16<<<ggrid, 256, 0, stream>>>(h1b, Wt[1], featf, N);
  k_eler<<<egrid, 256, 0, stream>>>(featf, al[1], ar[1], el, er, N);
  k_agg<<<agrid, 256, 0, stream>>>(featf, el, er, rowptr, eidx, src, out, nullptr, h2b, N);

  // layer 2: no residual; output: d_out (f32)
  k_gemm_bf16<<<ggrid, 256, 0, stream>>>(h2b, Wt[2], featf, N);
  k_eler<<<egrid, 256, 0, stream>>>(featf, al[2], ar[2], el, er, N);
  k_agg<<<agrid, 256, 0, stream>>>(featf, el, er, rowptr, eidx, src, nullptr, out, nullptr, N);
}

// Round 3
// 488.496 us; speedup vs baseline: 1.0998x; 1.0998x over previous
//
#include <hip/hip_runtime.h>
#include <stdint.h>

typedef __bf16 bf16x8 __attribute__((ext_vector_type(8)));
typedef float f32x4 __attribute__((ext_vector_type(4)));

__device__ __forceinline__ ushort f2bf(float f) {
  uint32_t u = __float_as_uint(f);
  u += 0x7FFFu + ((u >> 16) & 1u);
  return (ushort)(u >> 16);
}
__device__ __forceinline__ float bf2f(ushort u) {
  return __uint_as_float(((uint32_t)u) << 16);
}

// ---------------- cast f32 -> bf16, 8 elems/thread ----------------
__global__ __launch_bounds__(256) void k_cast_bf16(const float* __restrict__ in,
                                                   ushort* __restrict__ out, long n) {
  long i = ((long)blockIdx.x * 256 + threadIdx.x) * 8;
  if (i >= n) return;
  float4 a = *(const float4*)(in + i);
  float4 b = *(const float4*)(in + i + 4);
  uint4 r;
  r.x = (uint)f2bf(a.x) | ((uint)f2bf(a.y) << 16);
  r.y = (uint)f2bf(a.z) | ((uint)f2bf(a.w) << 16);
  r.z = (uint)f2bf(b.x) | ((uint)f2bf(b.y) << 16);
  r.w = (uint)f2bf(b.z) | ((uint)f2bf(b.w) << 16);
  *(uint4*)(out + i) = r;
}

// ---------------- W [K=256, N=256] f32 -> Wt [N,K] bf16 ----------------
__global__ void k_transpose_w(const float* __restrict__ W, ushort* __restrict__ Wt) {
  int n = blockIdx.x;      // output row (N dim)
  int k = threadIdx.x;     // 0..255
  Wt[n * 256 + k] = f2bf(W[k * 256 + n]);
}

// ---------------- CSR build ----------------
__global__ __launch_bounds__(256) void k_count(const int* __restrict__ dst, int* __restrict__ cnt, int E) {
  int i = blockIdx.x * 256 + threadIdx.x;
  if (i < E) atomicAdd(&cnt[dst[i]], 1);
}

__global__ __launch_bounds__(1024) void k_exscan(const int* __restrict__ cnt,
                                                 int* __restrict__ rowptr, int N) {
  __shared__ int wsum[16];
  __shared__ int carry;
  int tid = threadIdx.x, lane = tid & 63, wv = tid >> 6;
  if (tid == 0) { carry = 0; rowptr[0] = 0; }
  __syncthreads();
  for (int base = 0; base < N; base += 1024) {
    int i = base + tid;
    int v = (i < N) ? cnt[i] : 0;
    int x = v;
#pragma unroll
    for (int off = 1; off < 64; off <<= 1) {
      int y = __shfl_up(x, off);
      if (lane >= off) x += y;
    }
    if (lane == 63) wsum[wv] = x;
    __syncthreads();
    if (wv == 0) {
      int s = (lane < 16) ? wsum[lane] : 0;
#pragma unroll
      for (int off = 1; off < 16; off <<= 1) {
        int y = __shfl_up(s, off);
        if (lane >= off) s += y;
      }
      if (lane < 16) wsum[lane] = s;
    }
    __syncthreads();
    int woff = wv ? wsum[wv - 1] : 0;
    int total = wsum[15];
    int c = carry;
    if (i < N) rowptr[i + 1] = c + woff + x;
    __syncthreads();
    if (tid == 0) carry = c + total;
    __syncthreads();
  }
}

__global__ __launch_bounds__(256) void k_scatter(const int* __restrict__ dst,
                                                 const int* __restrict__ rowptr,
                                                 int* __restrict__ fill,
                                                 int* __restrict__ eidx, int E) {
  int e = blockIdx.x * 256 + threadIdx.x;
  if (e < E) {
    int d = dst[e];
    int p = atomicAdd(&fill[d], 1);
    eidx[rowptr[d] + p] = e;
  }
}

// ------- bf16 MFMA GEMM: C_bf16[M,256] = A_bf16[M,256] @ Wt_bf16^T (Wt is [N,K]) -------
#define BM 128
#define BN 128
#define BK 64
#define LDK 72  // padded LDS row (bf16 elems)

__global__ __launch_bounds__(256) void k_gemm_bf16(const ushort* __restrict__ A,
                                                   const ushort* __restrict__ Bt,
                                                   ushort* __restrict__ C, int M) {
  __shared__ __align__(16) ushort As[BM * LDK];
  __shared__ __align__(16) ushort Bs[BN * LDK];
  const int K = 256, N = 256;
  int bm = blockIdx.x * BM;
  int bn = blockIdx.y * BN;
  int tid = threadIdx.x;
  int lane = tid & 63, wid = tid >> 6;
  int wr = wid >> 1, wc = wid & 1;  // wave 64x64 subtile

  f32x4 acc[4][4];
#pragma unroll
  for (int mi = 0; mi < 4; ++mi)
#pragma unroll
    for (int ni = 0; ni < 4; ++ni) acc[mi][ni] = (f32x4){0.f, 0.f, 0.f, 0.f};

  for (int kt = 0; kt < K; kt += BK) {
#pragma unroll
    for (int i = 0; i < 4; ++i) {  // A tile 128x64
      int flat = i * 2048 + tid * 8;
      int r = flat >> 6, c = flat & 63;
      int gr = bm + r;
      uint4 v = {0u, 0u, 0u, 0u};
      if (gr < M) v = *(const uint4*)(A + (size_t)gr * K + kt + c);
      *(uint4*)(As + r * LDK + c) = v;
    }
#pragma unroll
    for (int i = 0; i < 4; ++i) {  // B tile 128x64 (rows of Wt, N=256 always in-bounds)
      int flat = i * 2048 + tid * 8;
      int r = flat >> 6, c = flat & 63;
      uint4 v = *(const uint4*)(Bt + (size_t)(bn + r) * K + kt + c);
      *(uint4*)(Bs + r * LDK + c) = v;
    }
    __syncthreads();
#pragma unroll
    for (int s = 0; s < 2; ++s) {  // two K=32 slices
      bf16x8 af[4], bfr[4];
      int cc = s * 32 + (lane >> 4) * 8;
#pragma unroll
      for (int mi = 0; mi < 4; ++mi) {
        int r = wr * 64 + mi * 16 + (lane & 15);
        af[mi] = *(const bf16x8*)(As + r * LDK + cc);
      }
#pragma unroll
      for (int ni = 0; ni < 4; ++ni) {
        int r = wc * 64 + ni * 16 + (lane & 15);
        bfr[ni] = *(const bf16x8*)(Bs + r * LDK + cc);
      }
#pragma unroll
      for (int mi = 0; mi < 4; ++mi)
#pragma unroll
        for (int ni = 0; ni < 4; ++ni)
          acc[mi][ni] = __builtin_amdgcn_mfma_f32_16x16x32_bf16(af[mi], bfr[ni], acc[mi][ni], 0, 0, 0);
    }
    __syncthreads();
  }
  // C/D layout: col = lane&15, row = (lane>>4)*4 + reg
#pragma unroll
  for (int mi = 0; mi < 4; ++mi) {
#pragma unroll
    for (int j = 0; j < 4; ++j) {
      int gr = bm + wr * 64 + mi * 16 + (lane >> 4) * 4 + j;
      if (gr < M) {
#pragma unroll
        for (int ni = 0; ni < 4; ++ni) {
          int gc = bn + wc * 64 + ni * 16 + (lane & 15);
          C[(size_t)gr * N + gc] = f2bf(acc[mi][ni][j]);
        }
      }
    }
  }
}

// ---------------- el/er from bf16 feat: one thread per (node, head) ----------------
__global__ __launch_bounds__(256) void k_eler(const ushort* __restrict__ feat,
                                              const float* __restrict__ al,
                                              const float* __restrict__ ar,
                                              float* __restrict__ el, float* __restrict__ er,
                                              int N) {
  int idx = blockIdx.x * 256 + threadIdx.x;
  if (idx >= N * 4) return;
  int n = idx >> 2, h = idx & 3;
  const ushort* f = feat + (size_t)n * 256 + h * 64;
  const float* alp = al + h * 64;
  const float* arp = ar + h * 64;
  float sl = 0.f, sr = 0.f;
#pragma unroll
  for (int d0 = 0; d0 < 64; d0 += 8) {
    uint4 v = *(const uint4*)(f + d0);
    float f0 = __uint_as_float(v.x << 16), f1 = __uint_as_float(v.x & 0xFFFF0000u);
    float f2 = __uint_as_float(v.y << 16), f3 = __uint_as_float(v.y & 0xFFFF0000u);
    float f4 = __uint_as_float(v.z << 16), f5 = __uint_as_float(v.z & 0xFFFF0000u);
    float f6 = __uint_as_float(v.w << 16), f7 = __uint_as_float(v.w & 0xFFFF0000u);
    sl += f0 * alp[d0] + f1 * alp[d0 + 1] + f2 * alp[d0 + 2] + f3 * alp[d0 + 3] +
          f4 * alp[d0 + 4] + f5 * alp[d0 + 5] + f6 * alp[d0 + 6] + f7 * alp[d0 + 7];
    sr += f0 * arp[d0] + f1 * arp[d0 + 1] + f2 * arp[d0 + 2] + f3 * arp[d0 + 3] +
          f4 * arp[d0 + 4] + f5 * arp[d0 + 5] + f6 * arp[d0 + 6] + f7 * arp[d0 + 7];
  }
  el[idx] = sl;
  er[idx] = sr;
}

// ------- fused edge-softmax + aggregation: one wave per dst node, lane owns dims 4l..4l+3 -------
__global__ __launch_bounds__(256) void k_agg(const ushort* __restrict__ feat,
                                             const float* __restrict__ el,
                                             const float* __restrict__ er,
                                             const int* __restrict__ rowptr,
                                             const int* __restrict__ eidx,
                                             const int* __restrict__ src,
                                             const float* __restrict__ resid,
                                             float* __restrict__ out_f32,
                                             ushort* __restrict__ out_bf16, int N) {
  int wv = threadIdx.x >> 6;
  int lane = threadIdx.x & 63;
  int n = blockIdx.x * 4 + wv;
  if (n >= N) return;
  int e0 = rowptr[n], e1 = rowptr[n + 1];
  int h = lane >> 4;                       // head this lane serves
  float ern = er[(size_t)n * 4 + h];

  // phase 1: per-head max; each 16-lane head-group covers all edges (stride 16)
  float m = -1e30f;
  for (int j = e0 + (lane & 15); j < e1; j += 16) {
    int s = src[eidx[j]];
    float v = el[(size_t)s * 4 + h] + ern;
    v = v >= 0.f ? v : 0.2f * v;
    m = fmaxf(m, v);
  }
  m = fmaxf(m, __shfl_xor(m, 1));
  m = fmaxf(m, __shfl_xor(m, 2));
  m = fmaxf(m, __shfl_xor(m, 4));
  m = fmaxf(m, __shfl_xor(m, 8));

  // phase 2: serial over edges; lane gathers its 4 bf16 dims (8B) per edge
  float den = 0.f;
  float a0 = 0.f, a1 = 0.f, a2 = 0.f, a3 = 0.f;
  const ushort* fb = feat + (size_t)lane * 4;
  for (int j = e0; j < e1; ++j) {
    int s = src[eidx[j]];
    float v = el[(size_t)s * 4 + h] + ern;
    v = v >= 0.f ? v : 0.2f * v;
    float w = __expf(v - m);
    den += w;
    uint2 f = *(const uint2*)(fb + (size_t)s * 256);
    a0 += w * __uint_as_float(f.x << 16);
    a1 += w * __uint_as_float(f.x & 0xFFFF0000u);
    a2 += w * __uint_as_float(f.y << 16);
    a3 += w * __uint_as_float(f.y & 0xFFFF0000u);
  }
  float inv = 1.f / fmaxf(den, 1e-9f);
  float o0 = a0 * inv, o1 = a1 * inv, o2 = a2 * inv, o3 = a3 * inv;

  size_t base = (size_t)n * 256 + lane * 4;
  if (resid) {
    float4 r = *(const float4*)(resid + base);
    o0 += r.x; o1 += r.y; o2 += r.z; o3 += r.w;
  }
  o0 = fmaxf(o0, 0.f); o1 = fmaxf(o1, 0.f); o2 = fmaxf(o2, 0.f); o3 = fmaxf(o3, 0.f);
  if (out_f32) {
    float4 o = {o0, o1, o2, o3};
    *(float4*)(out_f32 + base) = o;
  }
  if (out_bf16) {
    uint2 p;
    p.x = (uint)f2bf(o0) | ((uint)f2bf(o1) << 16);
    p.y = (uint)f2bf(o2) | ((uint)f2bf(o3) << 16);
    *(uint2*)(out_bf16 + base) = p;
  }
}

extern "C" void kernel_launch(void* const* d_in, const int* in_sizes, int n_in,
                              void* d_out, int out_size, void* d_ws, size_t ws_size,
                              hipStream_t stream) {
  const float* x = (const float*)d_in[0];
  const int* src = (const int*)d_in[1];
  const int* dst = (const int*)d_in[2];
  const float* W[3]  = {(const float*)d_in[3], (const float*)d_in[6], (const float*)d_in[9]};
  const float* al[3] = {(const float*)d_in[4], (const float*)d_in[7], (const float*)d_in[10]};
  const float* ar[3] = {(const float*)d_in[5], (const float*)d_in[8], (const float*)d_in[11]};
  const int N = in_sizes[0] / 256;
  const int E = in_sizes[1];
  float* out = (float*)d_out;

  char* ws = (char*)d_ws;
  size_t off = 0;
  auto alloc = [&](size_t bytes) -> void* {
    void* p = ws + off;
    off += (bytes + 255) & ~(size_t)255;
    return p;
  };
  ushort* xb    = (ushort*)alloc((size_t)N * 256 * 2);   // bf16 cast of x
  ushort* h1b   = (ushort*)alloc((size_t)N * 256 * 2);   // layer0 out, bf16 (GEMM input)
  ushort* h2b   = (ushort*)alloc((size_t)N * 256 * 2);   // layer1 out, bf16 (GEMM input)
  ushort* featb = (ushort*)alloc((size_t)N * 256 * 2);   // GEMM output, bf16
  float*  el    = (float*)alloc((size_t)N * 4 * 4);
  float*  er    = (float*)alloc((size_t)N * 4 * 4);
  ushort* Wt[3];
  for (int i = 0; i < 3; ++i) Wt[i] = (ushort*)alloc(256 * 256 * 2);
  int* cnt    = (int*)alloc((size_t)N * 4);
  int* rowptr = (int*)alloc((size_t)(N + 1) * 4);
  int* fill   = (int*)alloc((size_t)N * 4);
  int* eidx   = (int*)alloc((size_t)E * 4);
  // d_out doubles as the f32 h1 buffer (residual input for layer 1);
  // it is fully overwritten by layer 2's aggregation.

  long totx = (long)N * 256;
  k_cast_bf16<<<(int)((totx / 8 + 255) / 256), 256, 0, stream>>>(x, xb, totx);
  for (int i = 0; i < 3; ++i) k_transpose_w<<<256, 256, 0, stream>>>(W[i], Wt[i]);
  hipMemsetAsync(cnt, 0, (size_t)N * 4, stream);
  hipMemsetAsync(fill, 0, (size_t)N * 4, stream);
  k_count<<<(E + 255) / 256, 256, 0, stream>>>(dst, cnt, E);
  k_exscan<<<1, 1024, 0, stream>>>(cnt, rowptr, N);
  k_scatter<<<(E + 255) / 256, 256, 0, stream>>>(dst, rowptr, fill, eidx, E);

  dim3 ggrid((N + BM - 1) / BM, 2);
  dim3 agrid((N + 3) / 4);
  int egrid = (N * 4 + 255) / 256;

  // layer 0: residual = x (f32); outputs: d_out (f32 h1) + h1b (bf16)
  k_gemm_bf16<<<ggrid, 256, 0, stream>>>(xb, Wt[0], featb, N);
  k_eler<<<egrid, 256, 0, stream>>>(featb, al[0], ar[0], el, er, N);
  k_agg<<<agrid, 256, 0, stream>>>(featb, el, er, rowptr, eidx, src, x, out, h1b, N);

  // layer 1: residual = d_out (f32 h1); output: h2b (bf16 only)
  k_gemm_bf16<<<ggrid, 256, 0, stream>>>(h1b, Wt[1], featb, N);
  k_eler<<<egrid, 256, 0, stream>>>(featb, al[1], ar[1], el, er, N);
  k_agg<<<agrid, 256, 0, stream>>>(featb, el, er, rowptr, eidx, src, out, nullptr, h2b, N);

  // layer 2: no residual; output: d_out (f32)
  k_gemm_bf16<<<ggrid, 256, 0, stream>>>(h2b, Wt[2], featb, N);
  k_eler<<<egrid, 256, 0, stream>>>(featb, al[2], ar[2], el, er, N);
  k_agg<<<agrid, 256, 0, stream>>>(featb, el, er, rowptr, eidx, src, nullptr, out, nullptr, N);
}

// Round 4
// 383.463 us; speedup vs baseline: 1.4011x; 1.2739x over previous
//
#include <hip/hip_runtime.h>
#include <stdint.h>

typedef __bf16 bf16x8 __attribute__((ext_vector_type(8)));
typedef float f32x4 __attribute__((ext_vector_type(4)));

__device__ __forceinline__ ushort f2bf(float f) {
  uint32_t u = __float_as_uint(f);
  u += 0x7FFFu + ((u >> 16) & 1u);
  return (ushort)(u >> 16);
}
__device__ __forceinline__ float bflo(uint u) { return __uint_as_float(u << 16); }
__device__ __forceinline__ float bfhi(uint u) { return __uint_as_float(u & 0xFFFF0000u); }

// ---------------- cast f32 -> bf16, 8 elems/thread ----------------
__global__ __launch_bounds__(256) void k_cast_bf16(const float* __restrict__ in,
                                                   ushort* __restrict__ out, long n) {
  long i = ((long)blockIdx.x * 256 + threadIdx.x) * 8;
  if (i >= n) return;
  float4 a = *(const float4*)(in + i);
  float4 b = *(const float4*)(in + i + 4);
  uint4 r;
  r.x = (uint)f2bf(a.x) | ((uint)f2bf(a.y) << 16);
  r.y = (uint)f2bf(a.z) | ((uint)f2bf(a.w) << 16);
  r.z = (uint)f2bf(b.x) | ((uint)f2bf(b.y) << 16);
  r.w = (uint)f2bf(b.z) | ((uint)f2bf(b.w) << 16);
  *(uint4*)(out + i) = r;
}

// ---------------- W [K=256, N=256] f32 -> Wt [N,K] bf16 ----------------
__global__ void k_transpose_w(const float* __restrict__ W, ushort* __restrict__ Wt) {
  int n = blockIdx.x;
  int k = threadIdx.x;
  Wt[n * 256 + k] = f2bf(W[k * 256 + n]);
}

// ---------------- CSR build ----------------
__global__ __launch_bounds__(256) void k_count(const int* __restrict__ dst, int* __restrict__ cnt, int E) {
  int i = blockIdx.x * 256 + threadIdx.x;
  if (i < E) atomicAdd(&cnt[dst[i]], 1);
}

__global__ __launch_bounds__(1024) void k_exscan(const int* __restrict__ cnt,
                                                 int* __restrict__ rowptr, int N) {
  __shared__ int wsum[16];
  __shared__ int carry;
  int tid = threadIdx.x, lane = tid & 63, wv = tid >> 6;
  if (tid == 0) { carry = 0; rowptr[0] = 0; }
  __syncthreads();
  for (int base = 0; base < N; base += 1024) {
    int i = base + tid;
    int v = (i < N) ? cnt[i] : 0;
    int x = v;
#pragma unroll
    for (int off = 1; off < 64; off <<= 1) {
      int y = __shfl_up(x, off);
      if (lane >= off) x += y;
    }
    if (lane == 63) wsum[wv] = x;
    __syncthreads();
    if (wv == 0) {
      int s = (lane < 16) ? wsum[lane] : 0;
#pragma unroll
      for (int off = 1; off < 16; off <<= 1) {
        int y = __shfl_up(s, off);
        if (lane >= off) s += y;
      }
      if (lane < 16) wsum[lane] = s;
    }
    __syncthreads();
    int woff = wv ? wsum[wv - 1] : 0;
    int total = wsum[15];
    int c = carry;
    if (i < N) rowptr[i + 1] = c + woff + x;
    __syncthreads();
    if (tid == 0) carry = c + total;
    __syncthreads();
  }
}

// scatter: store SOURCE NODE INDEX (not edge id) in CSR slot order
__global__ __launch_bounds__(256) void k_scatter(const int* __restrict__ dst,
                                                 const int* __restrict__ src,
                                                 const int* __restrict__ rowptr,
                                                 int* __restrict__ fill,
                                                 int* __restrict__ esrc, int E) {
  int e = blockIdx.x * 256 + threadIdx.x;
  if (e < E) {
    int d = dst[e];
    int p = atomicAdd(&fill[d], 1);
    esrc[rowptr[d] + p] = src[e];
  }
}

// ------- bf16 MFMA GEMM: C_bf16[M,256] = A_bf16[M,256] @ Wt_bf16^T (Wt is [N,K]) -------
#define BM 128
#define BN 128
#define BK 64
#define LDK 72  // padded LDS row (bf16 elems)

__global__ __launch_bounds__(256) void k_gemm_bf16(const ushort* __restrict__ A,
                                                   const ushort* __restrict__ Bt,
                                                   ushort* __restrict__ C, int M) {
  __shared__ __align__(16) ushort As[BM * LDK];
  __shared__ __align__(16) ushort Bs[BN * LDK];
  const int K = 256, N = 256;
  int bm = blockIdx.x * BM;
  int bn = blockIdx.y * BN;
  int tid = threadIdx.x;
  int lane = tid & 63, wid = tid >> 6;
  int wr = wid >> 1, wc = wid & 1;

  f32x4 acc[4][4];
#pragma unroll
  for (int mi = 0; mi < 4; ++mi)
#pragma unroll
    for (int ni = 0; ni < 4; ++ni) acc[mi][ni] = (f32x4){0.f, 0.f, 0.f, 0.f};

  for (int kt = 0; kt < K; kt += BK) {
#pragma unroll
    for (int i = 0; i < 4; ++i) {
      int flat = i * 2048 + tid * 8;
      int r = flat >> 6, c = flat & 63;
      int gr = bm + r;
      uint4 v = {0u, 0u, 0u, 0u};
      if (gr < M) v = *(const uint4*)(A + (size_t)gr * K + kt + c);
      *(uint4*)(As + r * LDK + c) = v;
    }
#pragma unroll
    for (int i = 0; i < 4; ++i) {
      int flat = i * 2048 + tid * 8;
      int r = flat >> 6, c = flat & 63;
      uint4 v = *(const uint4*)(Bt + (size_t)(bn + r) * K + kt + c);
      *(uint4*)(Bs + r * LDK + c) = v;
    }
    __syncthreads();
#pragma unroll
    for (int s = 0; s < 2; ++s) {
      bf16x8 af[4], bfr[4];
      int cc = s * 32 + (lane >> 4) * 8;
#pragma unroll
      for (int mi = 0; mi < 4; ++mi) {
        int r = wr * 64 + mi * 16 + (lane & 15);
        af[mi] = *(const bf16x8*)(As + r * LDK + cc);
      }
#pragma unroll
      for (int ni = 0; ni < 4; ++ni) {
        int r = wc * 64 + ni * 16 + (lane & 15);
        bfr[ni] = *(const bf16x8*)(Bs + r * LDK + cc);
      }
#pragma unroll
      for (int mi = 0; mi < 4; ++mi)
#pragma unroll
        for (int ni = 0; ni < 4; ++ni)
          acc[mi][ni] = __builtin_amdgcn_mfma_f32_16x16x32_bf16(af[mi], bfr[ni], acc[mi][ni], 0, 0, 0);
    }
    __syncthreads();
  }
#pragma unroll
  for (int mi = 0; mi < 4; ++mi) {
#pragma unroll
    for (int j = 0; j < 4; ++j) {
      int gr = bm + wr * 64 + mi * 16 + (lane >> 4) * 4 + j;
      if (gr < M) {
#pragma unroll
        for (int ni = 0; ni < 4; ++ni) {
          int gc = bn + wc * 64 + ni * 16 + (lane & 15);
          C[(size_t)gr * N + gc] = f2bf(acc[mi][ni][j]);
        }
      }
    }
  }
}

// ---------------- el/er from bf16 feat ----------------
__global__ __launch_bounds__(256) void k_eler(const ushort* __restrict__ feat,
                                              const float* __restrict__ al,
                                              const float* __restrict__ ar,
                                              float* __restrict__ el, float* __restrict__ er,
                                              int N) {
  int idx = blockIdx.x * 256 + threadIdx.x;
  if (idx >= N * 4) return;
  int n = idx >> 2, h = idx & 3;
  const ushort* f = feat + (size_t)n * 256 + h * 64;
  const float* alp = al + h * 64;
  const float* arp = ar + h * 64;
  float sl = 0.f, sr = 0.f;
#pragma unroll
  for (int d0 = 0; d0 < 64; d0 += 8) {
    uint4 v = *(const uint4*)(f + d0);
    float f0 = bflo(v.x), f1 = bfhi(v.x);
    float f2 = bflo(v.y), f3 = bfhi(v.y);
    float f4 = bflo(v.z), f5 = bfhi(v.z);
    float f6 = bflo(v.w), f7 = bfhi(v.w);
    sl += f0 * alp[d0] + f1 * alp[d0 + 1] + f2 * alp[d0 + 2] + f3 * alp[d0 + 3] +
          f4 * alp[d0 + 4] + f5 * alp[d0 + 5] + f6 * alp[d0 + 6] + f7 * alp[d0 + 7];
    sr += f0 * arp[d0] + f1 * arp[d0 + 1] + f2 * arp[d0 + 2] + f3 * arp[d0 + 3] +
          f4 * arp[d0 + 4] + f5 * arp[d0 + 5] + f6 * arp[d0 + 6] + f7 * arp[d0 + 7];
  }
  el[idx] = sl;
  er[idx] = sr;
}

// ------- fused edge-softmax + aggregation -------
// one wave per dst node; lane = (head h = lane>>4, sub = lane&15); lane owns dims 4*lane..4*lane+3
#define CAP 128  // edges cached in LDS per node (slow fallback above this)

__global__ __launch_bounds__(256) void k_agg(const ushort* __restrict__ feat,
                                             const float* __restrict__ el,
                                             const float* __restrict__ er,
                                             const int* __restrict__ rowptr,
                                             const int* __restrict__ esrc,
                                             const float* __restrict__ resid,
                                             float* __restrict__ out_f32,
                                             ushort* __restrict__ out_bf16, int N) {
  __shared__ float lw[4][CAP * 4];  // per-wave logit/weight cache [edge][head]
  int wv = threadIdx.x >> 6;
  int lane = threadIdx.x & 63;
  int n = blockIdx.x * 4 + wv;
  if (n >= N) return;
  int e0 = rowptr[n], e1 = rowptr[n + 1];
  int deg = e1 - e0;
  int h = lane >> 4, sub = lane & 15;
  float ern = er[(size_t)n * 4 + h];
  float* lwp = lw[wv];

  // phase 1: logits (parallel, stride 16 per head group) -> LDS; track per-head max
  float m = -1e30f;
  for (int jj = sub; jj < deg; jj += 16) {
    int s = esrc[e0 + jj];
    float v = el[(size_t)s * 4 + h] + ern;
    v = v >= 0.f ? v : 0.2f * v;
    if (jj < CAP) lwp[jj * 4 + h] = v;
    m = fmaxf(m, v);
  }
  m = fmaxf(m, __shfl_xor(m, 1));
  m = fmaxf(m, __shfl_xor(m, 2));
  m = fmaxf(m, __shfl_xor(m, 4));
  m = fmaxf(m, __shfl_xor(m, 8));

  // phase 2a: w = exp(v - m) (parallel), denominator reduce
  float den = 0.f;
  for (int jj = sub; jj < deg; jj += 16) {
    float v;
    if (jj < CAP) {
      v = lwp[jj * 4 + h];
    } else {
      int s = esrc[e0 + jj];
      v = el[(size_t)s * 4 + h] + ern;
      v = v >= 0.f ? v : 0.2f * v;
    }
    float w = __expf(v - m);
    if (jj < CAP) lwp[jj * 4 + h] = w;
    den += w;
  }
  den += __shfl_xor(den, 1);
  den += __shfl_xor(den, 2);
  den += __shfl_xor(den, 4);
  den += __shfl_xor(den, 8);
  float inv = 1.f / fmaxf(den, 1e-9f);

  // phase 2b: serial gather+FMA, 4-wide unroll (independent gathers in flight)
  float a0 = 0.f, a1 = 0.f, a2 = 0.f, a3 = 0.f;
  const ushort* fb = feat + (size_t)lane * 4;
  if (deg <= CAP) {
    int j = 0;
    for (; j + 4 <= deg; j += 4) {
      int s0 = esrc[e0 + j], s1 = esrc[e0 + j + 1], s2 = esrc[e0 + j + 2], s3 = esrc[e0 + j + 3];
      uint2 f0 = *(const uint2*)(fb + (size_t)s0 * 256);
      uint2 f1 = *(const uint2*)(fb + (size_t)s1 * 256);
      uint2 f2 = *(const uint2*)(fb + (size_t)s2 * 256);
      uint2 f3 = *(const uint2*)(fb + (size_t)s3 * 256);
      float w0 = lwp[(j + 0) * 4 + h];
      float w1 = lwp[(j + 1) * 4 + h];
      float w2 = lwp[(j + 2) * 4 + h];
      float w3 = lwp[(j + 3) * 4 + h];
      a0 += w0 * bflo(f0.x); a1 += w0 * bfhi(f0.x); a2 += w0 * bflo(f0.y); a3 += w0 * bfhi(f0.y);
      a0 += w1 * bflo(f1.x); a1 += w1 * bfhi(f1.x); a2 += w1 * bflo(f1.y); a3 += w1 * bfhi(f1.y);
      a0 += w2 * bflo(f2.x); a1 += w2 * bfhi(f2.x); a2 += w2 * bflo(f2.y); a3 += w2 * bfhi(f2.y);
      a0 += w3 * bflo(f3.x); a1 += w3 * bfhi(f3.x); a2 += w3 * bflo(f3.y); a3 += w3 * bfhi(f3.y);
    }
    for (; j < deg; ++j) {
      int s = esrc[e0 + j];
      uint2 f = *(const uint2*)(fb + (size_t)s * 256);
      float w = lwp[j * 4 + h];
      a0 += w * bflo(f.x); a1 += w * bfhi(f.x); a2 += w * bflo(f.y); a3 += w * bfhi(f.y);
    }
  } else {
    for (int j = 0; j < deg; ++j) {
      int s = esrc[e0 + j];
      float w;
      if (j < CAP) {
        w = lwp[j * 4 + h];
      } else {
        float v = el[(size_t)s * 4 + h] + ern;
        v = v >= 0.f ? v : 0.2f * v;
        w = __expf(v - m);
      }
      uint2 f = *(const uint2*)(fb + (size_t)s * 256);
      a0 += w * bflo(f.x); a1 += w * bfhi(f.x); a2 += w * bflo(f.y); a3 += w * bfhi(f.y);
    }
  }
  float o0 = a0 * inv, o1 = a1 * inv, o2 = a2 * inv, o3 = a3 * inv;

  size_t base = (size_t)n * 256 + lane * 4;
  if (resid) {
    float4 r = *(const float4*)(resid + base);
    o0 += r.x; o1 += r.y; o2 += r.z; o3 += r.w;
  }
  o0 = fmaxf(o0, 0.f); o1 = fmaxf(o1, 0.f); o2 = fmaxf(o2, 0.f); o3 = fmaxf(o3, 0.f);
  if (out_f32) {
    float4 o = {o0, o1, o2, o3};
    *(float4*)(out_f32 + base) = o;
  }
  if (out_bf16) {
    uint2 p;
    p.x = (uint)f2bf(o0) | ((uint)f2bf(o1) << 16);
    p.y = (uint)f2bf(o2) | ((uint)f2bf(o3) << 16);
    *(uint2*)(out_bf16 + base) = p;
  }
}

extern "C" void kernel_launch(void* const* d_in, const int* in_sizes, int n_in,
                              void* d_out, int out_size, void* d_ws, size_t ws_size,
                              hipStream_t stream) {
  const float* x = (const float*)d_in[0];
  const int* src = (const int*)d_in[1];
  const int* dst = (const int*)d_in[2];
  const float* W[3]  = {(const float*)d_in[3], (const float*)d_in[6], (const float*)d_in[9]};
  const float* al[3] = {(const float*)d_in[4], (const float*)d_in[7], (const float*)d_in[10]};
  const float* ar[3] = {(const float*)d_in[5], (const float*)d_in[8], (const float*)d_in[11]};
  const int N = in_sizes[0] / 256;
  const int E = in_sizes[1];
  float* out = (float*)d_out;

  char* ws = (char*)d_ws;
  size_t off = 0;
  auto alloc = [&](size_t bytes) -> void* {
    void* p = ws + off;
    off += (bytes + 255) & ~(size_t)255;
    return p;
  };
  ushort* xb    = (ushort*)alloc((size_t)N * 256 * 2);
  ushort* h1b   = (ushort*)alloc((size_t)N * 256 * 2);
  ushort* h2b   = (ushort*)alloc((size_t)N * 256 * 2);
  ushort* featb = (ushort*)alloc((size_t)N * 256 * 2);
  float*  el    = (float*)alloc((size_t)N * 4 * 4);
  float*  er    = (float*)alloc((size_t)N * 4 * 4);
  ushort* Wt[3];
  for (int i = 0; i < 3; ++i) Wt[i] = (ushort*)alloc(256 * 256 * 2);
  int* cnt    = (int*)alloc((size_t)N * 4);
  int* rowptr = (int*)alloc((size_t)(N + 1) * 4);
  int* fill   = (int*)alloc((size_t)N * 4);
  int* esrc   = (int*)alloc((size_t)E * 4);
  // d_out doubles as the f32 h1 buffer (residual for layer 1); fully overwritten by layer 2.

  long totx = (long)N * 256;
  k_cast_bf16<<<(int)((totx / 8 + 255) / 256), 256, 0, stream>>>(x, xb, totx);
  for (int i = 0; i < 3; ++i) k_transpose_w<<<256, 256, 0, stream>>>(W[i], Wt[i]);
  hipMemsetAsync(cnt, 0, (size_t)N * 4, stream);
  hipMemsetAsync(fill, 0, (size_t)N * 4, stream);
  k_count<<<(E + 255) / 256, 256, 0, stream>>>(dst, cnt, E);
  k_exscan<<<1, 1024, 0, stream>>>(cnt, rowptr, N);
  k_scatter<<<(E + 255) / 256, 256, 0, stream>>>(dst, src, rowptr, fill, esrc, E);

  dim3 ggrid((N + BM - 1) / BM, 2);
  dim3 agrid((N + 3) / 4);
  int egrid = (N * 4 + 255) / 256;

  // layer 0: residual = x (f32); outputs: d_out (f32 h1) + h1b (bf16)
  k_gemm_bf16<<<ggrid, 256, 0, stream>>>(xb, Wt[0], featb, N);
  k_eler<<<egrid, 256, 0, stream>>>(featb, al[0], ar[0], el, er, N);
  k_agg<<<agrid, 256, 0, stream>>>(featb, el, er, rowptr, esrc, x, out, h1b, N);

  // layer 1: residual = d_out (f32 h1); output: h2b (bf16)
  k_gemm_bf16<<<ggrid, 256, 0, stream>>>(h1b, Wt[1], featb, N);
  k_eler<<<egrid, 256, 0, stream>>>(featb, al[1], ar[1], el, er, N);
  k_agg<<<agrid, 256, 0, stream>>>(featb, el, er, rowptr, esrc, out, nullptr, h2b, N);

  // layer 2: no residual; output: d_out (f32)
  k_gemm_bf16<<<ggrid, 256, 0, stream>>>(h2b, Wt[2], featb, N);
  k_eler<<<egrid, 256, 0, stream>>>(featb, al[2], ar[2], el, er, N);
  k_agg<<<agrid, 256, 0, stream>>>(featb, el, er, rowptr, esrc, nullptr, out, nullptr, N);
}

// Round 5
// 339.972 us; speedup vs baseline: 1.5803x; 1.1279x over previous
//
#include <hip/hip_runtime.h>
#include <stdint.h>

typedef __bf16 bf16x8 __attribute__((ext_vector_type(8)));
typedef float f32x4 __attribute__((ext_vector_type(4)));

typedef __attribute__((address_space(1))) const unsigned int gu32;
typedef __attribute__((address_space(3))) unsigned int lu32;
__device__ __forceinline__ void gl_lds16(const void* g, void* l) {
  __builtin_amdgcn_global_load_lds((gu32*)g, (lu32*)l, 16, 0, 0);
}

__device__ __forceinline__ ushort f2bf(float f) {
  uint32_t u = __float_as_uint(f);
  u += 0x7FFFu + ((u >> 16) & 1u);
  return (ushort)(u >> 16);
}
__device__ __forceinline__ float bflo(uint u) { return __uint_as_float(u << 16); }
__device__ __forceinline__ float bfhi(uint u) { return __uint_as_float(u & 0xFFFF0000u); }

// ---------------- cast f32 -> bf16, 8 elems/thread ----------------
__global__ __launch_bounds__(256) void k_cast_bf16(const float* __restrict__ in,
                                                   ushort* __restrict__ out, long n) {
  long i = ((long)blockIdx.x * 256 + threadIdx.x) * 8;
  if (i >= n) return;
  float4 a = *(const float4*)(in + i);
  float4 b = *(const float4*)(in + i + 4);
  uint4 r;
  r.x = (uint)f2bf(a.x) | ((uint)f2bf(a.y) << 16);
  r.y = (uint)f2bf(a.z) | ((uint)f2bf(a.w) << 16);
  r.z = (uint)f2bf(b.x) | ((uint)f2bf(b.y) << 16);
  r.w = (uint)f2bf(b.z) | ((uint)f2bf(b.w) << 16);
  *(uint4*)(out + i) = r;
}

// ---------------- W [K=256, N=256] f32 -> Wt [N,K] bf16 ----------------
__global__ void k_transpose_w(const float* __restrict__ W, ushort* __restrict__ Wt) {
  int n = blockIdx.x;
  int k = threadIdx.x;
  Wt[n * 256 + k] = f2bf(W[k * 256 + n]);
}

// ---------------- CSR build ----------------
__global__ __launch_bounds__(256) void k_count(const int* __restrict__ dst, int* __restrict__ cnt, int E) {
  int i = blockIdx.x * 256 + threadIdx.x;
  if (i < E) atomicAdd(&cnt[dst[i]], 1);
}

// hierarchical scan, step 1: per-block inclusive scan of cnt -> rowptr[i+1]; block totals -> bsum
__global__ __launch_bounds__(1024) void k_scan1(const int* __restrict__ cnt,
                                                int* __restrict__ rowptr,
                                                int* __restrict__ bsum, int N) {
  __shared__ int wsum[16];
  int tid = threadIdx.x, lane = tid & 63, wv = tid >> 6;
  int i = blockIdx.x * 1024 + tid;
  int v = (i < N) ? cnt[i] : 0;
  int x = v;
#pragma unroll
  for (int off = 1; off < 64; off <<= 1) {
    int y = __shfl_up(x, off);
    if (lane >= off) x += y;
  }
  if (lane == 63) wsum[wv] = x;
  __syncthreads();
  if (wv == 0) {
    int s = (lane < 16) ? wsum[lane] : 0;
#pragma unroll
    for (int off = 1; off < 16; off <<= 1) {
      int y = __shfl_up(s, off);
      if (lane >= off) s += y;
    }
    if (lane < 16) wsum[lane] = s;
  }
  __syncthreads();
  x += wv ? wsum[wv - 1] : 0;
  if (i < N) rowptr[i + 1] = x;  // inclusive within block (offset added in scan3)
  if (tid == 0) bsum[blockIdx.x] = wsum[15];
}

// step 2: single wave, exclusive scan of G block sums (in place)
__global__ void k_scan2(int* __restrict__ bsum, int G) {
  int lane = threadIdx.x & 63;
  int carry = 0;
  for (int base = 0; base < G; base += 64) {
    int b = base + lane;
    int v = (b < G) ? bsum[b] : 0;
    int x = v;
#pragma unroll
    for (int off = 1; off < 64; off <<= 1) {
      int y = __shfl_up(x, off);
      if (lane >= off) x += y;
    }
    if (b < G) bsum[b] = carry + x - v;  // exclusive
    carry += __shfl(x, 63);
  }
}

// step 3: add block offsets
__global__ __launch_bounds__(1024) void k_scan3(int* __restrict__ rowptr,
                                                const int* __restrict__ bsum, int N) {
  int i = blockIdx.x * 1024 + threadIdx.x;
  if (i < N) rowptr[i + 1] += bsum[blockIdx.x];
  if (blockIdx.x == 0 && threadIdx.x == 0) rowptr[0] = 0;
}

// scatter: store SOURCE NODE INDEX in CSR slot order
__global__ __launch_bounds__(256) void k_scatter(const int* __restrict__ dst,
                                                 const int* __restrict__ src,
                                                 const int* __restrict__ rowptr,
                                                 int* __restrict__ fill,
                                                 int* __restrict__ esrc, int E) {
  int e = blockIdx.x * 256 + threadIdx.x;
  if (e < E) {
    int d = dst[e];
    int p = atomicAdd(&fill[d], 1);
    esrc[rowptr[d] + p] = src[e];
  }
}

// ------- bf16 MFMA GEMM: C_bf16[M,256] = A_bf16[M,256] @ Wt_bf16^T (Wt is [N,K]) -------
#define BM 128
#define BN 128
#define BK 64

__global__ __launch_bounds__(256) void k_gemm_bf16(const ushort* __restrict__ A,
                                                   const ushort* __restrict__ Bt,
                                                   ushort* __restrict__ C, int M) {
  __shared__ __align__(16) ushort As[BM * BK];
  __shared__ __align__(16) ushort Bs[BN * BK];
  const int K = 256, N = 256;
  int bn = blockIdx.x * BN;   // fast dim: the 2 bn-blocks sharing an A tile are adjacent
  int bm = blockIdx.y * BM;
  int tid = threadIdx.x;
  int lane = tid & 63, wid = tid >> 6;
  int wr = wid >> 1, wc = wid & 1;

  f32x4 acc[4][4];
#pragma unroll
  for (int mi = 0; mi < 4; ++mi)
#pragma unroll
    for (int ni = 0; ni < 4; ++ni) acc[mi][ni] = (f32x4){0.f, 0.f, 0.f, 0.f};

  for (int kt = 0; kt < K; kt += BK) {
#pragma unroll
    for (int i = 0; i < 4; ++i) {
      int flat = i * 2048 + tid * 8;       // bf16 elems; 16B per lane
      int r = flat >> 6, c = flat & 63;
      int gr = bm + r;
      if (gr >= M) gr = M - 1;             // clamp; those output rows are discarded
      gl_lds16(A + (size_t)gr * K + kt + c, As + i * 2048 + wid * 512);
      gl_lds16(Bt + (size_t)(bn + r) * K + kt + c, Bs + i * 2048 + wid * 512);
    }
    __syncthreads();
#pragma unroll
    for (int s = 0; s < 2; ++s) {
      bf16x8 af[4], bfr[4];
      int cc = s * 32 + (lane >> 4) * 8;
#pragma unroll
      for (int mi = 0; mi < 4; ++mi) {
        int r = wr * 64 + mi * 16 + (lane & 15);
        af[mi] = *(const bf16x8*)(As + r * BK + cc);
      }
#pragma unroll
      for (int ni = 0; ni < 4; ++ni) {
        int r = wc * 64 + ni * 16 + (lane & 15);
        bfr[ni] = *(const bf16x8*)(Bs + r * BK + cc);
      }
#pragma unroll
      for (int mi = 0; mi < 4; ++mi)
#pragma unroll
        for (int ni = 0; ni < 4; ++ni)
          acc[mi][ni] = __builtin_amdgcn_mfma_f32_16x16x32_bf16(af[mi], bfr[ni], acc[mi][ni], 0, 0, 0);
    }
    __syncthreads();
  }
#pragma unroll
  for (int mi = 0; mi < 4; ++mi) {
#pragma unroll
    for (int j = 0; j < 4; ++j) {
      int gr = bm + wr * 64 + mi * 16 + (lane >> 4) * 4 + j;
      if (gr < M) {
#pragma unroll
        for (int ni = 0; ni < 4; ++ni) {
          int gc = bn + wc * 64 + ni * 16 + (lane & 15);
          C[(size_t)gr * N + gc] = f2bf(acc[mi][ni][j]);
        }
      }
    }
  }
}

// ---------------- el/er from bf16 feat ----------------
__global__ __launch_bounds__(256) void k_eler(const ushort* __restrict__ feat,
                                              const float* __restrict__ al,
                                              const float* __restrict__ ar,
                                              float* __restrict__ el, float* __restrict__ er,
                                              int N) {
  int idx = blockIdx.x * 256 + threadIdx.x;
  if (idx >= N * 4) return;
  int n = idx >> 2, h = idx & 3;
  const ushort* f = feat + (size_t)n * 256 + h * 64;
  const float* alp = al + h * 64;
  const float* arp = ar + h * 64;
  float sl = 0.f, sr = 0.f;
#pragma unroll
  for (int d0 = 0; d0 < 64; d0 += 8) {
    uint4 v = *(const uint4*)(f + d0);
    float f0 = bflo(v.x), f1 = bfhi(v.x);
    float f2 = bflo(v.y), f3 = bfhi(v.y);
    float f4 = bflo(v.z), f5 = bfhi(v.z);
    float f6 = bflo(v.w), f7 = bfhi(v.w);
    sl += f0 * alp[d0] + f1 * alp[d0 + 1] + f2 * alp[d0 + 2] + f3 * alp[d0 + 3] +
          f4 * alp[d0 + 4] + f5 * alp[d0 + 5] + f6 * alp[d0 + 6] + f7 * alp[d0 + 7];
    sr += f0 * arp[d0] + f1 * arp[d0 + 1] + f2 * arp[d0 + 2] + f3 * arp[d0 + 3] +
          f4 * arp[d0 + 4] + f5 * arp[d0 + 5] + f6 * arp[d0 + 6] + f7 * arp[d0 + 7];
  }
  el[idx] = sl;
  er[idx] = sr;
}

// ------- fused edge-softmax + aggregation -------
// one wave per dst node; head h = lane>>4, sub = lane&15; lane owns dims 4*lane..4*lane+3
#define CAP 128

__global__ __launch_bounds__(256) void k_agg(const ushort* __restrict__ feat,
                                             const float* __restrict__ el,
                                             const float* __restrict__ er,
                                             const int* __restrict__ rowptr,
                                             const int* __restrict__ esrc,
                                             const float* __restrict__ resid_f32,
                                             const ushort* __restrict__ resid_bf16,
                                             float* __restrict__ out_f32,
                                             ushort* __restrict__ out_bf16, int N) {
  __shared__ float lw[4][CAP * 4];
  int wv = threadIdx.x >> 6;
  int lane = threadIdx.x & 63;
  int n = blockIdx.x * 4 + wv;
  if (n >= N) return;
  int e0 = rowptr[n], e1 = rowptr[n + 1];
  int deg = e1 - e0;
  int h = lane >> 4, sub = lane & 15;
  float ern = er[(size_t)n * 4 + h];
  float* lwp = lw[wv];

  // phase 1: logits -> LDS (parallel, stride 16 per head group); per-head max
  float m = -1e30f;
  for (int jj = sub; jj < deg; jj += 16) {
    int s = esrc[e0 + jj];
    float v = el[(size_t)s * 4 + h] + ern;
    v = v >= 0.f ? v : 0.2f * v;
    if (jj < CAP) lwp[jj * 4 + h] = v;
    m = fmaxf(m, v);
  }
  m = fmaxf(m, __shfl_xor(m, 1));
  m = fmaxf(m, __shfl_xor(m, 2));
  m = fmaxf(m, __shfl_xor(m, 4));
  m = fmaxf(m, __shfl_xor(m, 8));

  // phase 2a: w = exp(v - m), denominator reduce
  float den = 0.f;
  for (int jj = sub; jj < deg; jj += 16) {
    float v;
    if (jj < CAP) {
      v = lwp[jj * 4 + h];
    } else {
      int s = esrc[e0 + jj];
      v = el[(size_t)s * 4 + h] + ern;
      v = v >= 0.f ? v : 0.2f * v;
    }
    float w = __expf(v - m);
    if (jj < CAP) lwp[jj * 4 + h] = w;
    den += w;
  }
  den += __shfl_xor(den, 1);
  den += __shfl_xor(den, 2);
  den += __shfl_xor(den, 4);
  den += __shfl_xor(den, 8);
  float inv = 1.f / fmaxf(den, 1e-9f);

  // phase 2b: serial gather+FMA, 8-wide unroll
  float a0 = 0.f, a1 = 0.f, a2 = 0.f, a3 = 0.f;
  const ushort* fb = feat + (size_t)lane * 4;
  if (deg <= CAP) {
    int j = 0;
    for (; j + 8 <= deg; j += 8) {
      int s[8];
      uint2 f[8];
      float w[8];
#pragma unroll
      for (int t = 0; t < 8; ++t) s[t] = esrc[e0 + j + t];
#pragma unroll
      for (int t = 0; t < 8; ++t) f[t] = *(const uint2*)(fb + (size_t)s[t] * 256);
#pragma unroll
      for (int t = 0; t < 8; ++t) w[t] = lwp[(j + t) * 4 + h];
#pragma unroll
      for (int t = 0; t < 8; ++t) {
        a0 += w[t] * bflo(f[t].x); a1 += w[t] * bfhi(f[t].x);
        a2 += w[t] * bflo(f[t].y); a3 += w[t] * bfhi(f[t].y);
      }
    }
    for (; j < deg; ++j) {
      int s = esrc[e0 + j];
      uint2 f = *(const uint2*)(fb + (size_t)s * 256);
      float w = lwp[j * 4 + h];
      a0 += w * bflo(f.x); a1 += w * bfhi(f.x); a2 += w * bflo(f.y); a3 += w * bfhi(f.y);
    }
  } else {
    for (int j = 0; j < deg; ++j) {
      int s = esrc[e0 + j];
      float w;
      if (j < CAP) {
        w = lwp[j * 4 + h];
      } else {
        float v = el[(size_t)s * 4 + h] + ern;
        v = v >= 0.f ? v : 0.2f * v;
        w = __expf(v - m);
      }
      uint2 f = *(const uint2*)(fb + (size_t)s * 256);
      a0 += w * bflo(f.x); a1 += w * bfhi(f.x); a2 += w * bflo(f.y); a3 += w * bfhi(f.y);
    }
  }
  float o0 = a0 * inv, o1 = a1 * inv, o2 = a2 * inv, o3 = a3 * inv;

  size_t base = (size_t)n * 256 + lane * 4;
  if (resid_f32) {
    float4 r = *(const float4*)(resid_f32 + base);
    o0 += r.x; o1 += r.y; o2 += r.z; o3 += r.w;
  } else if (resid_bf16) {
    uint2 r = *(const uint2*)(resid_bf16 + base);
    o0 += bflo(r.x); o1 += bfhi(r.x); o2 += bflo(r.y); o3 += bfhi(r.y);
  }
  o0 = fmaxf(o0, 0.f); o1 = fmaxf(o1, 0.f); o2 = fmaxf(o2, 0.f); o3 = fmaxf(o3, 0.f);
  if (out_f32) {
    float4 o = {o0, o1, o2, o3};
    *(float4*)(out_f32 + base) = o;
  }
  if (out_bf16) {
    uint2 p;
    p.x = (uint)f2bf(o0) | ((uint)f2bf(o1) << 16);
    p.y = (uint)f2bf(o2) | ((uint)f2bf(o3) << 16);
    *(uint2*)(out_bf16 + base) = p;
  }
}

extern "C" void kernel_launch(void* const* d_in, const int* in_sizes, int n_in,
                              void* d_out, int out_size, void* d_ws, size_t ws_size,
                              hipStream_t stream) {
  const float* x = (const float*)d_in[0];
  const int* src = (const int*)d_in[1];
  const int* dst = (const int*)d_in[2];
  const float* W[3]  = {(const float*)d_in[3], (const float*)d_in[6], (const float*)d_in[9]};
  const float* al[3] = {(const float*)d_in[4], (const float*)d_in[7], (const float*)d_in[10]};
  const float* ar[3] = {(const float*)d_in[5], (const float*)d_in[8], (const float*)d_in[11]};
  const int N = in_sizes[0] / 256;
  const int E = in_sizes[1];
  float* out = (float*)d_out;

  char* ws = (char*)d_ws;
  size_t off = 0;
  auto alloc = [&](size_t bytes) -> void* {
    void* p = ws + off;
    off += (bytes + 255) & ~(size_t)255;
    return p;
  };
  ushort* xb    = (ushort*)alloc((size_t)N * 256 * 2);
  ushort* h1b   = (ushort*)alloc((size_t)N * 256 * 2);
  ushort* h2b   = (ushort*)alloc((size_t)N * 256 * 2);
  ushort* featb = (ushort*)alloc((size_t)N * 256 * 2);
  float*  el    = (float*)alloc((size_t)N * 4 * 4);
  float*  er    = (float*)alloc((size_t)N * 4 * 4);
  ushort* Wt[3];
  for (int i = 0; i < 3; ++i) Wt[i] = (ushort*)alloc(256 * 256 * 2);
  int* cnt    = (int*)alloc((size_t)N * 4);
  int* rowptr = (int*)alloc((size_t)(N + 1) * 4);
  int* fill   = (int*)alloc((size_t)N * 4);
  int* esrc   = (int*)alloc((size_t)E * 4);
  int* bsum   = (int*)alloc(4096);

  long totx = (long)N * 256;
  int G = (N + 1023) / 1024;
  k_cast_bf16<<<(int)((totx / 8 + 255) / 256), 256, 0, stream>>>(x, xb, totx);
  for (int i = 0; i < 3; ++i) k_transpose_w<<<256, 256, 0, stream>>>(W[i], Wt[i]);
  hipMemsetAsync(cnt, 0, (size_t)N * 4, stream);
  hipMemsetAsync(fill, 0, (size_t)N * 4, stream);
  k_count<<<(E + 255) / 256, 256, 0, stream>>>(dst, cnt, E);
  k_scan1<<<G, 1024, 0, stream>>>(cnt, rowptr, bsum, N);
  k_scan2<<<1, 64, 0, stream>>>(bsum, G);
  k_scan3<<<G, 1024, 0, stream>>>(rowptr, bsum, N);
  k_scatter<<<(E + 255) / 256, 256, 0, stream>>>(dst, src, rowptr, fill, esrc, E);

  dim3 ggrid(2, (N + BM - 1) / BM);   // bn fast, bm slow: A-tile reuse in L2
  dim3 agrid((N + 3) / 4);
  int egrid = (N * 4 + 255) / 256;

  // layer 0: residual = x (f32); output: h1b (bf16)
  k_gemm_bf16<<<ggrid, 256, 0, stream>>>(xb, Wt[0], featb, N);
  k_eler<<<egrid, 256, 0, stream>>>(featb, al[0], ar[0], el, er, N);
  k_agg<<<agrid, 256, 0, stream>>>(featb, el, er, rowptr, esrc, x, nullptr, nullptr, h1b, N);

  // layer 1: residual = h1b (bf16); output: h2b (bf16)
  k_gemm_bf16<<<ggrid, 256, 0, stream>>>(h1b, Wt[1], featb, N);
  k_eler<<<egrid, 256, 0, stream>>>(featb, al[1], ar[1], el, er, N);
  k_agg<<<agrid, 256, 0, stream>>>(featb, el, er, rowptr, esrc, nullptr, h1b, nullptr, h2b, N);

  // layer 2: no residual; output: d_out (f32)
  k_gemm_bf16<<<ggrid, 256, 0, stream>>>(h2b, Wt[2], featb, N);
  k_eler<<<egrid, 256, 0, stream>>>(featb, al[2], ar[2], el, er, N);
  k_agg<<<agrid, 256, 0, stream>>>(featb, el, er, rowptr, esrc, nullptr, nullptr, out, nullptr, N);
}

// Round 7
// 264.242 us; speedup vs baseline: 2.0332x; 1.2866x over previous
//
#include <hip/hip_runtime.h>
#include <stdint.h>

typedef __bf16 bf16x8 __attribute__((ext_vector_type(8)));
typedef float f32x4 __attribute__((ext_vector_type(4)));

typedef __attribute__((address_space(1))) const unsigned int gu32;
typedef __attribute__((address_space(3))) unsigned int lu32;
__device__ __forceinline__ void gl_lds16(const void* g, void* l) {
  __builtin_amdgcn_global_load_lds((gu32*)g, (lu32*)l, 16, 0, 0);
}

__device__ __forceinline__ ushort f2bf(float f) {
  uint32_t u = __float_as_uint(f);
  u += 0x7FFFu + ((u >> 16) & 1u);
  return (ushort)(u >> 16);
}
__device__ __forceinline__ float bflo(uint u) { return __uint_as_float(u << 16); }
__device__ __forceinline__ float bfhi(uint u) { return __uint_as_float(u & 0xFFFF0000u); }

// ---------------- cast f32 -> bf16, 8 elems/thread ----------------
__global__ __launch_bounds__(256) void k_cast_bf16(const float* __restrict__ in,
                                                   ushort* __restrict__ out, long n) {
  long i = ((long)blockIdx.x * 256 + threadIdx.x) * 8;
  if (i >= n) return;
  float4 a = *(const float4*)(in + i);
  float4 b = *(const float4*)(in + i + 4);
  uint4 r;
  r.x = (uint)f2bf(a.x) | ((uint)f2bf(a.y) << 16);
  r.y = (uint)f2bf(a.z) | ((uint)f2bf(a.w) << 16);
  r.z = (uint)f2bf(b.x) | ((uint)f2bf(b.y) << 16);
  r.w = (uint)f2bf(b.z) | ((uint)f2bf(b.w) << 16);
  *(uint4*)(out + i) = r;
}

// ---------------- all 3 weights: W[K=256,N=256] f32 -> Wt[N,K] bf16, tiled ----------------
__global__ __launch_bounds__(256) void k_transpose3(const float* __restrict__ W0,
                                                    const float* __restrict__ W1,
                                                    const float* __restrict__ W2,
                                                    ushort* __restrict__ T0,
                                                    ushort* __restrict__ T1,
                                                    ushort* __restrict__ T2) {
  __shared__ float t[64][65];
  const float* W = blockIdx.z == 0 ? W0 : (blockIdx.z == 1 ? W1 : W2);
  ushort* T = blockIdx.z == 0 ? T0 : (blockIdx.z == 1 ? T1 : T2);
  int r0 = blockIdx.y * 64, c0 = blockIdx.x * 64;
  int tr = threadIdx.x >> 4, tc = threadIdx.x & 15;
#pragma unroll
  for (int i = 0; i < 4; ++i) {
    int r = tr + i * 16;
    float4 v = *(const float4*)(W + (size_t)(r0 + r) * 256 + c0 + tc * 4);
    t[r][tc * 4 + 0] = v.x; t[r][tc * 4 + 1] = v.y;
    t[r][tc * 4 + 2] = v.z; t[r][tc * 4 + 3] = v.w;
  }
  __syncthreads();
#pragma unroll
  for (int i = 0; i < 4; ++i) {
    int nn = tr + i * 16;   // output row n = c0+nn
    int kk = tc * 4;        // output cols k = r0+kk..+3
    ushort4 o;
    o.x = f2bf(t[kk + 0][nn]); o.y = f2bf(t[kk + 1][nn]);
    o.z = f2bf(t[kk + 2][nn]); o.w = f2bf(t[kk + 3][nn]);
    *(ushort4*)(T + (size_t)(c0 + nn) * 256 + r0 + kk) = o;
  }
}

// ---------------- CSR build ----------------
__global__ __launch_bounds__(256) void k_count(const int* __restrict__ dst, int* __restrict__ cnt, int E) {
  int i = blockIdx.x * 256 + threadIdx.x;
  if (i < E) atomicAdd(&cnt[dst[i]], 1);
}

__global__ __launch_bounds__(1024) void k_scan1(const int* __restrict__ cnt,
                                                int* __restrict__ rowptr,
                                                int* __restrict__ bsum, int N) {
  __shared__ int wsum[16];
  int tid = threadIdx.x, lane = tid & 63, wv = tid >> 6;
  int i = blockIdx.x * 1024 + tid;
  int v = (i < N) ? cnt[i] : 0;
  int x = v;
#pragma unroll
  for (int off = 1; off < 64; off <<= 1) {
    int y = __shfl_up(x, off);
    if (lane >= off) x += y;
  }
  if (lane == 63) wsum[wv] = x;
  __syncthreads();
  if (wv == 0) {
    int s = (lane < 16) ? wsum[lane] : 0;
#pragma unroll
    for (int off = 1; off < 16; off <<= 1) {
      int y = __shfl_up(s, off);
      if (lane >= off) s += y;
    }
    if (lane < 16) wsum[lane] = s;
  }
  __syncthreads();
  x += wv ? wsum[wv - 1] : 0;
  if (i < N) rowptr[i + 1] = x;
  if (tid == 0) bsum[blockIdx.x] = wsum[15];
}

__global__ void k_scan2(int* __restrict__ bsum, int G) {
  int lane = threadIdx.x & 63;
  int carry = 0;
  for (int base = 0; base < G; base += 64) {
    int b = base + lane;
    int v = (b < G) ? bsum[b] : 0;
    int x = v;
#pragma unroll
    for (int off = 1; off < 64; off <<= 1) {
      int y = __shfl_up(x, off);
      if (lane >= off) x += y;
    }
    if (b < G) bsum[b] = carry + x - v;
    carry += __shfl(x, 63);
  }
}

__global__ __launch_bounds__(1024) void k_scan3(int* __restrict__ rowptr,
                                                const int* __restrict__ bsum, int N) {
  int i = blockIdx.x * 1024 + threadIdx.x;
  if (i < N) rowptr[i + 1] += bsum[blockIdx.x];
  if (blockIdx.x == 0 && threadIdx.x == 0) rowptr[0] = 0;
}

__global__ __launch_bounds__(256) void k_scatter(const int* __restrict__ dst,
                                                 const int* __restrict__ src,
                                                 const int* __restrict__ rowptr,
                                                 int* __restrict__ fill,
                                                 int* __restrict__ esrc, int E) {
  int e = blockIdx.x * 256 + threadIdx.x;
  if (e < E) {
    int d = dst[e];
    int p = atomicAdd(&fill[d], 1);
    esrc[rowptr[d] + p] = src[e];
  }
}

// ------- bf16 MFMA GEMM + fused el/er epilogue -------
// C_bf16[M,256] = A_bf16[M,256] @ Wt^T ; el/er[M,4] from f32 acc
// 2-phase pipeline (T3 minimal): stage(t+1) -> compute(t) -> vmcnt(0)+barrier
// LDS swizzle: linear gl_lds dest, source col-slot ^= row&7, read addr ^= (lane&7)<<3
#define BM 128
#define BN 128
#define BK 64

__global__ __launch_bounds__(256) void k_gemm_bf16(const ushort* __restrict__ A,
                                                   const ushort* __restrict__ Bt,
                                                   const float* __restrict__ al,
                                                   const float* __restrict__ ar,
                                                   ushort* __restrict__ C,
                                                   float* __restrict__ el,
                                                   float* __restrict__ er, int M) {
  __shared__ __align__(16) ushort As[2 * BM * BK];
  __shared__ __align__(16) ushort Bs[2 * BN * BK];
  const int K = 256, N = 256;
  int bn = blockIdx.x * BN;   // 2 bn-blocks sharing an A tile are adjacent in dispatch
  int bm = blockIdx.y * BM;
  int tid = threadIdx.x;
  int lane = tid & 63, wid = tid >> 6;
  int wr = wid >> 1, wc = wid & 1;

  f32x4 acc[4][4];
#pragma unroll
  for (int mi = 0; mi < 4; ++mi)
#pragma unroll
    for (int ni = 0; ni < 4; ++ni) acc[mi][ni] = (f32x4){0.f, 0.f, 0.f, 0.f};

  // staging: lane writes linear slot (r = i*32 + tid>>3, slot = tid&7);
  // source column-slot pre-swizzled so read-side XOR recovers it.
  auto stage = [&](int kt, int buf) {
#pragma unroll
    for (int i = 0; i < 4; ++i) {
      int r = i * 32 + (tid >> 3);
      int cs = (((tid & 7) ^ (r & 7)) << 3);
      int gr = bm + r;
      if (gr >= M) gr = M - 1;  // clamp; those rows' outputs are discarded
      gl_lds16(A + (size_t)gr * K + kt + cs, As + buf * 8192 + i * 2048 + wid * 512);
      gl_lds16(Bt + (size_t)(bn + r) * K + kt + cs, Bs + buf * 8192 + i * 2048 + wid * 512);
    }
  };

  stage(0, 0);
  asm volatile("s_waitcnt vmcnt(0)" ::: "memory");
  __builtin_amdgcn_s_barrier();

  int swz = (lane & 7) << 3;  // row&7 of every fragment row == lane&7
#pragma unroll
  for (int t = 0; t < 4; ++t) {
    int cur = t & 1;
    if (t < 3) stage((t + 1) * BK, cur ^ 1);
    const ushort* Ab = As + cur * 8192;
    const ushort* Bb = Bs + cur * 8192;
#pragma unroll
    for (int s = 0; s < 2; ++s) {
      bf16x8 af[4], bfr[4];
      int cc = s * 32 + (lane >> 4) * 8;
      int cs = cc ^ swz;
#pragma unroll
      for (int mi = 0; mi < 4; ++mi) {
        int r = wr * 64 + mi * 16 + (lane & 15);
        af[mi] = *(const bf16x8*)(Ab + r * BK + cs);
      }
#pragma unroll
      for (int ni = 0; ni < 4; ++ni) {
        int r = wc * 64 + ni * 16 + (lane & 15);
        bfr[ni] = *(const bf16x8*)(Bb + r * BK + cs);
      }
#pragma unroll
      for (int mi = 0; mi < 4; ++mi)
#pragma unroll
        for (int ni = 0; ni < 4; ++ni)
          acc[mi][ni] = __builtin_amdgcn_mfma_f32_16x16x32_bf16(af[mi], bfr[ni], acc[mi][ni], 0, 0, 0);
    }
    if (t < 3) {
      asm volatile("s_waitcnt vmcnt(0)" ::: "memory");
      __builtin_amdgcn_s_barrier();
    }
  }

  // C store (bf16)
#pragma unroll
  for (int mi = 0; mi < 4; ++mi) {
#pragma unroll
    for (int j = 0; j < 4; ++j) {
      int gr = bm + wr * 64 + mi * 16 + (lane >> 4) * 4 + j;
      if (gr < M) {
#pragma unroll
        for (int ni = 0; ni < 4; ++ni) {
          int gc = bn + wc * 64 + ni * 16 + (lane & 15);
          C[(size_t)gr * N + gc] = f2bf(acc[mi][ni][j]);
        }
      }
    }
  }

  // fused el/er: this wave's 64 cols == head h
  int h = (bn >> 6) + wc;
  float alv[4], arv[4];
#pragma unroll
  for (int ni = 0; ni < 4; ++ni) {
    int d = ni * 16 + (lane & 15);
    alv[ni] = al[h * 64 + d];
    arv[ni] = ar[h * 64 + d];
  }
#pragma unroll
  for (int mi = 0; mi < 4; ++mi) {
#pragma unroll
    for (int j = 0; j < 4; ++j) {
      float pel = acc[mi][0][j] * alv[0] + acc[mi][1][j] * alv[1] +
                  acc[mi][2][j] * alv[2] + acc[mi][3][j] * alv[3];
      float per = acc[mi][0][j] * arv[0] + acc[mi][1][j] * arv[1] +
                  acc[mi][2][j] * arv[2] + acc[mi][3][j] * arv[3];
#pragma unroll
      for (int off = 8; off >= 1; off >>= 1) {
        pel += __shfl_xor(pel, off);
        per += __shfl_xor(per, off);
      }
      int gr = bm + wr * 64 + mi * 16 + (lane >> 4) * 4 + j;
      if ((lane & 15) == 0 && gr < M) {
        el[(size_t)gr * 4 + h] = pel;
        er[(size_t)gr * 4 + h] = per;
      }
    }
  }
}

// ------- fused edge-softmax + aggregation -------
// one wave per dst node; head h = lane>>4, sub = lane&15; lane owns dims 4*lane..4*lane+3
#define CAP 128

__global__ __launch_bounds__(256) void k_agg(const ushort* __restrict__ feat,
                                             const float* __restrict__ el,
                                             const float* __restrict__ er,
                                             const int* __restrict__ rowptr,
                                             const int* __restrict__ esrc,
                                             const float* __restrict__ resid_f32,
                                             const ushort* __restrict__ resid_bf16,
                                             float* __restrict__ out_f32,
                                             ushort* __restrict__ out_bf16, int N) {
  __shared__ float lw[4][CAP * 4];
  int wv = threadIdx.x >> 6;
  int lane = threadIdx.x & 63;
  int n = blockIdx.x * 4 + wv;
  if (n >= N) return;
  int e0 = rowptr[n], e1 = rowptr[n + 1];
  int deg = e1 - e0;
  int h = lane >> 4, sub = lane & 15;
  float ern = er[(size_t)n * 4 + h];
  const ushort* fb = feat + (size_t)lane * 4;

  float a0 = 0.f, a1 = 0.f, a2 = 0.f, a3 = 0.f;
  float inv;

  if (deg <= 16) {
    // ---- register fast path (avg deg = 8): no LDS, no esrc re-read ----
    int s_reg = 0;
    float v = -1e30f;
    if (sub < deg) {
      s_reg = esrc[e0 + sub];
      v = el[(size_t)s_reg * 4 + h] + ern;
      v = v >= 0.f ? v : 0.2f * v;
    }
    float m = v;
    m = fmaxf(m, __shfl_xor(m, 1));
    m = fmaxf(m, __shfl_xor(m, 2));
    m = fmaxf(m, __shfl_xor(m, 4));
    m = fmaxf(m, __shfl_xor(m, 8));
    float w_reg = (sub < deg) ? __expf(v - m) : 0.f;
    float den = w_reg;
    den += __shfl_xor(den, 1);
    den += __shfl_xor(den, 2);
    den += __shfl_xor(den, 4);
    den += __shfl_xor(den, 8);
    inv = 1.f / fmaxf(den, 1e-9f);
    int hb = h << 4;
    int j = 0;
    for (; j + 4 <= deg; j += 4) {
      int s0 = __shfl(s_reg, j), s1 = __shfl(s_reg, j + 1);
      int s2 = __shfl(s_reg, j + 2), s3 = __shfl(s_reg, j + 3);
      uint2 f0 = *(const uint2*)(fb + (size_t)s0 * 256);
      uint2 f1 = *(const uint2*)(fb + (size_t)s1 * 256);
      uint2 f2 = *(const uint2*)(fb + (size_t)s2 * 256);
      uint2 f3 = *(const uint2*)(fb + (size_t)s3 * 256);
      float w0 = __shfl(w_reg, hb + j), w1 = __shfl(w_reg, hb + j + 1);
      float w2 = __shfl(w_reg, hb + j + 2), w3 = __shfl(w_reg, hb + j + 3);
      a0 += w0 * bflo(f0.x); a1 += w0 * bfhi(f0.x); a2 += w0 * bflo(f0.y); a3 += w0 * bfhi(f0.y);
      a0 += w1 * bflo(f1.x); a1 += w1 * bfhi(f1.x); a2 += w1 * bflo(f1.y); a3 += w1 * bfhi(f1.y);
      a0 += w2 * bflo(f2.x); a1 += w2 * bfhi(f2.x); a2 += w2 * bflo(f2.y); a3 += w2 * bfhi(f2.y);
      a0 += w3 * bflo(f3.x); a1 += w3 * bfhi(f3.x); a2 += w3 * bflo(f3.y); a3 += w3 * bfhi(f3.y);
    }
    for (; j < deg; ++j) {
      int sj = __shfl(s_reg, j);
      uint2 f = *(const uint2*)(fb + (size_t)sj * 256);
      float wj = __shfl(w_reg, hb + j);
      a0 += wj * bflo(f.x); a1 += wj * bfhi(f.x); a2 += wj * bflo(f.y); a3 += wj * bfhi(f.y);
    }
  } else {
    // ---- LDS path (deg > 16), with >CAP fallback ----
    float* lwp = lw[wv];
    float m = -1e30f;
    for (int jj = sub; jj < deg; jj += 16) {
      int s = esrc[e0 + jj];
      float v = el[(size_t)s * 4 + h] + ern;
      v = v >= 0.f ? v : 0.2f * v;
      if (jj < CAP) lwp[jj * 4 + h] = v;
      m = fmaxf(m, v);
    }
    m = fmaxf(m, __shfl_xor(m, 1));
    m = fmaxf(m, __shfl_xor(m, 2));
    m = fmaxf(m, __shfl_xor(m, 4));
    m = fmaxf(m, __shfl_xor(m, 8));
    float den = 0.f;
    for (int jj = sub; jj < deg; jj += 16) {
      float v;
      if (jj < CAP) {
        v = lwp[jj * 4 + h];
      } else {
        int s = esrc[e0 + jj];
        v = el[(size_t)s * 4 + h] + ern;
        v = v >= 0.f ? v : 0.2f * v;
      }
      float w = __expf(v - m);
      if (jj < CAP) lwp[jj * 4 + h] = w;
      den += w;
    }
    den += __shfl_xor(den, 1);
    den += __shfl_xor(den, 2);
    den += __shfl_xor(den, 4);
    den += __shfl_xor(den, 8);
    inv = 1.f / fmaxf(den, 1e-9f);

    if (deg <= CAP) {
      int j = 0;
      for (; j + 8 <= deg; j += 8) {
        int s[8];
        uint2 f[8];
        float w[8];
#pragma unroll
        for (int t = 0; t < 8; ++t) s[t] = esrc[e0 + j + t];
#pragma unroll
        for (int t = 0; t < 8; ++t) f[t] = *(const uint2*)(fb + (size_t)s[t] * 256);
#pragma unroll
        for (int t = 0; t < 8; ++t) w[t] = lwp[(j + t) * 4 + h];
#pragma unroll
        for (int t = 0; t < 8; ++t) {
          a0 += w[t] * bflo(f[t].x); a1 += w[t] * bfhi(f[t].x);
          a2 += w[t] * bflo(f[t].y); a3 += w[t] * bfhi(f[t].y);
        }
      }
      for (; j < deg; ++j) {
        int s = esrc[e0 + j];
        uint2 f = *(const uint2*)(fb + (size_t)s * 256);
        float w = lwp[j * 4 + h];
        a0 += w * bflo(f.x); a1 += w * bfhi(f.x); a2 += w * bflo(f.y); a3 += w * bfhi(f.y);
      }
    } else {
      for (int j = 0; j < deg; ++j) {
        int s = esrc[e0 + j];
        float w;
        if (j < CAP) {
          w = lwp[j * 4 + h];
        } else {
          float v = el[(size_t)s * 4 + h] + ern;
          v = v >= 0.f ? v : 0.2f * v;
          w = __expf(v - m);
        }
        uint2 f = *(const uint2*)(fb + (size_t)s * 256);
        a0 += w * bflo(f.x); a1 += w * bfhi(f.x); a2 += w * bflo(f.y); a3 += w * bfhi(f.y);
      }
    }
  }

  float o0 = a0 * inv, o1 = a1 * inv, o2 = a2 * inv, o3 = a3 * inv;
  size_t base = (size_t)n * 256 + lane * 4;
  if (resid_f32) {
    float4 r = *(const float4*)(resid_f32 + base);
    o0 += r.x; o1 += r.y; o2 += r.z; o3 += r.w;
  } else if (resid_bf16) {
    uint2 r = *(const uint2*)(resid_bf16 + base);
    o0 += bflo(r.x); o1 += bfhi(r.x); o2 += bflo(r.y); o3 += bfhi(r.y);
  }
  o0 = fmaxf(o0, 0.f); o1 = fmaxf(o1, 0.f); o2 = fmaxf(o2, 0.f); o3 = fmaxf(o3, 0.f);
  if (out_f32) {
    float4 o = {o0, o1, o2, o3};
    *(float4*)(out_f32 + base) = o;
  }
  if (out_bf16) {
    uint2 p;
    p.x = (uint)f2bf(o0) | ((uint)f2bf(o1) << 16);
    p.y = (uint)f2bf(o2) | ((uint)f2bf(o3) << 16);
    *(uint2*)(out_bf16 + base) = p;
  }
}

extern "C" void kernel_launch(void* const* d_in, const int* in_sizes, int n_in,
                              void* d_out, int out_size, void* d_ws, size_t ws_size,
                              hipStream_t stream) {
  const float* x = (const float*)d_in[0];
  const int* src = (const int*)d_in[1];
  const int* dst = (const int*)d_in[2];
  const float* W[3]  = {(const float*)d_in[3], (const float*)d_in[6], (const float*)d_in[9]};
  const float* al[3] = {(const float*)d_in[4], (const float*)d_in[7], (const float*)d_in[10]};
  const float* ar[3] = {(const float*)d_in[5], (const float*)d_in[8], (const float*)d_in[11]};
  const int N = in_sizes[0] / 256;
  const int E = in_sizes[1];
  float* out = (float*)d_out;

  char* ws = (char*)d_ws;
  size_t off = 0;
  auto alloc = [&](size_t bytes) -> void* {
    void* p = ws + off;
    off += (bytes + 255) & ~(size_t)255;
    return p;
  };
  ushort* xb    = (ushort*)alloc((size_t)N * 256 * 2);
  ushort* h1b   = (ushort*)alloc((size_t)N * 256 * 2);
  ushort* h2b   = (ushort*)alloc((size_t)N * 256 * 2);
  ushort* featb = (ushort*)alloc((size_t)N * 256 * 2);
  float*  el    = (float*)alloc((size_t)N * 4 * 4);
  float*  er    = (float*)alloc((size_t)N * 4 * 4);
  ushort* Wt[3];
  for (int i = 0; i < 3; ++i) Wt[i] = (ushort*)alloc(256 * 256 * 2);
  int* cntfill = (int*)alloc((size_t)N * 2 * 4);  // cnt + fill, ONE block: memset covers both fully
  int* cnt  = cntfill;
  int* fill = cntfill + N;
  int* rowptr = (int*)alloc((size_t)(N + 1) * 4);
  int* esrc   = (int*)alloc((size_t)E * 4);
  int* bsum   = (int*)alloc(4096);

  long totx = (long)N * 256;
  int G = (N + 1023) / 1024;
  k_cast_bf16<<<(int)((totx / 8 + 255) / 256), 256, 0, stream>>>(x, xb, totx);
  k_transpose3<<<dim3(4, 4, 3), 256, 0, stream>>>(W[0], W[1], W[2], Wt[0], Wt[1], Wt[2]);
  hipMemsetAsync(cntfill, 0, (size_t)N * 2 * 4, stream);
  k_count<<<(E + 255) / 256, 256, 0, stream>>>(dst, cnt, E);
  k_scan1<<<G, 1024, 0, stream>>>(cnt, rowptr, bsum, N);
  k_scan2<<<1, 64, 0, stream>>>(bsum, G);
  k_scan3<<<G, 1024, 0, stream>>>(rowptr, bsum, N);
  k_scatter<<<(E + 255) / 256, 256, 0, stream>>>(dst, src, rowptr, fill, esrc, E);

  dim3 ggrid(2, (N + BM - 1) / BM);   // bn fast: A-tile reuse in L2
  dim3 agrid((N + 3) / 4);

  // layer 0: residual = x (f32); output: h1b (bf16)
  k_gemm_bf16<<<ggrid, 256, 0, stream>>>(xb, Wt[0], al[0], ar[0], featb, el, er, N);
  k_agg<<<agrid, 256, 0, stream>>>(featb, el, er, rowptr, esrc, x, nullptr, nullptr, h1b, N);

  // layer 1: residual = h1b (bf16); output: h2b (bf16)
  k_gemm_bf16<<<ggrid, 256, 0, stream>>>(h1b, Wt[1], al[1], ar[1], featb, el, er, N);
  k_agg<<<agrid, 256, 0, stream>>>(featb, el, er, rowptr, esrc, nullptr, h1b, nullptr, h2b, N);

  // layer 2: no residual; output: d_out (f32)
  k_gemm_bf16<<<ggrid, 256, 0, stream>>>(h2b, Wt[2], al[2], ar[2], featb, el, er, N);
  k_agg<<<agrid, 256, 0, stream>>>(featb, el, er, rowptr, esrc, nullptr, nullptr, out, nullptr, N);
}

// Round 8
// 253.961 us; speedup vs baseline: 2.1155x; 1.0405x over previous
//
#include <hip/hip_runtime.h>
#include <stdint.h>

typedef __bf16 bf16x8 __attribute__((ext_vector_type(8)));
typedef float f32x4 __attribute__((ext_vector_type(4)));

typedef __attribute__((address_space(1))) const unsigned int gu32;
typedef __attribute__((address_space(3))) unsigned int lu32;
__device__ __forceinline__ void gl_lds16(const void* g, void* l) {
  __builtin_amdgcn_global_load_lds((gu32*)g, (lu32*)l, 16, 0, 0);
}

__device__ __forceinline__ ushort f2bf(float f) {
  uint32_t u = __float_as_uint(f);
  u += 0x7FFFu + ((u >> 16) & 1u);
  return (ushort)(u >> 16);
}
__device__ __forceinline__ float bflo(uint u) { return __uint_as_float(u << 16); }
__device__ __forceinline__ float bfhi(uint u) { return __uint_as_float(u & 0xFFFF0000u); }

// ---------------- cast f32 -> bf16, 8 elems/thread ----------------
__global__ __launch_bounds__(256) void k_cast_bf16(const float* __restrict__ in,
                                                   ushort* __restrict__ out, long n) {
  long i = ((long)blockIdx.x * 256 + threadIdx.x) * 8;
  if (i >= n) return;
  float4 a = *(const float4*)(in + i);
  float4 b = *(const float4*)(in + i + 4);
  uint4 r;
  r.x = (uint)f2bf(a.x) | ((uint)f2bf(a.y) << 16);
  r.y = (uint)f2bf(a.z) | ((uint)f2bf(a.w) << 16);
  r.z = (uint)f2bf(b.x) | ((uint)f2bf(b.y) << 16);
  r.w = (uint)f2bf(b.z) | ((uint)f2bf(b.w) << 16);
  *(uint4*)(out + i) = r;
}

// ---------------- all 3 weights: W[K=256,N=256] f32 -> Wt[N,K] bf16, tiled ----------------
__global__ __launch_bounds__(256) void k_transpose3(const float* __restrict__ W0,
                                                    const float* __restrict__ W1,
                                                    const float* __restrict__ W2,
                                                    ushort* __restrict__ T0,
                                                    ushort* __restrict__ T1,
                                                    ushort* __restrict__ T2) {
  __shared__ float t[64][65];
  const float* W = blockIdx.z == 0 ? W0 : (blockIdx.z == 1 ? W1 : W2);
  ushort* T = blockIdx.z == 0 ? T0 : (blockIdx.z == 1 ? T1 : T2);
  int r0 = blockIdx.y * 64, c0 = blockIdx.x * 64;
  int tr = threadIdx.x >> 4, tc = threadIdx.x & 15;
#pragma unroll
  for (int i = 0; i < 4; ++i) {
    int r = tr + i * 16;
    float4 v = *(const float4*)(W + (size_t)(r0 + r) * 256 + c0 + tc * 4);
    t[r][tc * 4 + 0] = v.x; t[r][tc * 4 + 1] = v.y;
    t[r][tc * 4 + 2] = v.z; t[r][tc * 4 + 3] = v.w;
  }
  __syncthreads();
#pragma unroll
  for (int i = 0; i < 4; ++i) {
    int nn = tr + i * 16;   // output row n = c0+nn
    int kk = tc * 4;        // output cols k = r0+kk..+3
    ushort4 o;
    o.x = f2bf(t[kk + 0][nn]); o.y = f2bf(t[kk + 1][nn]);
    o.z = f2bf(t[kk + 2][nn]); o.w = f2bf(t[kk + 3][nn]);
    *(ushort4*)(T + (size_t)(c0 + nn) * 256 + r0 + kk) = o;
  }
}

// ---------------- CSR build ----------------
__global__ __launch_bounds__(256) void k_count(const int* __restrict__ dst, int* __restrict__ cnt, int E) {
  int i = blockIdx.x * 256 + threadIdx.x;
  if (i < E) atomicAdd(&cnt[dst[i]], 1);
}

__global__ __launch_bounds__(1024) void k_scan1(const int* __restrict__ cnt,
                                                int* __restrict__ rowptr,
                                                int* __restrict__ bsum, int N) {
  __shared__ int wsum[16];
  int tid = threadIdx.x, lane = tid & 63, wv = tid >> 6;
  int i = blockIdx.x * 1024 + tid;
  int v = (i < N) ? cnt[i] : 0;
  int x = v;
#pragma unroll
  for (int off = 1; off < 64; off <<= 1) {
    int y = __shfl_up(x, off);
    if (lane >= off) x += y;
  }
  if (lane == 63) wsum[wv] = x;
  __syncthreads();
  if (wv == 0) {
    int s = (lane < 16) ? wsum[lane] : 0;
#pragma unroll
    for (int off = 1; off < 16; off <<= 1) {
      int y = __shfl_up(s, off);
      if (lane >= off) s += y;
    }
    if (lane < 16) wsum[lane] = s;
  }
  __syncthreads();
  x += wv ? wsum[wv - 1] : 0;
  if (i < N) rowptr[i + 1] = x;
  if (tid == 0) bsum[blockIdx.x] = wsum[15];
}

__global__ void k_scan2(int* __restrict__ bsum, int G) {
  int lane = threadIdx.x & 63;
  int carry = 0;
  for (int base = 0; base < G; base += 64) {
    int b = base + lane;
    int v = (b < G) ? bsum[b] : 0;
    int x = v;
#pragma unroll
    for (int off = 1; off < 64; off <<= 1) {
      int y = __shfl_up(x, off);
      if (lane >= off) x += y;
    }
    if (b < G) bsum[b] = carry + x - v;
    carry += __shfl(x, 63);
  }
}

__global__ __launch_bounds__(1024) void k_scan3(int* __restrict__ rowptr,
                                                const int* __restrict__ bsum, int N) {
  int i = blockIdx.x * 1024 + threadIdx.x;
  if (i < N) rowptr[i + 1] += bsum[blockIdx.x];
  if (blockIdx.x == 0 && threadIdx.x == 0) rowptr[0] = 0;
}

__global__ __launch_bounds__(256) void k_scatter(const int* __restrict__ dst,
                                                 const int* __restrict__ src,
                                                 const int* __restrict__ rowptr,
                                                 int* __restrict__ fill,
                                                 int* __restrict__ esrc, int E) {
  int e = blockIdx.x * 256 + threadIdx.x;
  if (e < E) {
    int d = dst[e];
    int p = atomicAdd(&fill[d], 1);
    esrc[rowptr[d] + p] = src[e];
  }
}

// ------- bf16 MFMA GEMM + fused el/er epilogue, 512 threads (8 waves) -------
// C_bf16[M,256] = A_bf16[M,256] @ Wt^T ; el/er[M,4] from f32 acc
// wave tile 32 rows x 64 cols (wc owns a full head); 2 blocks/CU x 8 waves = 16 waves/CU
// LDS swizzle (verified r7): linear gl_lds dest, source col-slot ^= r&7, read addr ^= (lane&7)<<3
#define BM 128
#define BN 128
#define BK 64

__global__ __launch_bounds__(512) void k_gemm_bf16(const ushort* __restrict__ A,
                                                   const ushort* __restrict__ Bt,
                                                   const float* __restrict__ al,
                                                   const float* __restrict__ ar,
                                                   ushort* __restrict__ C,
                                                   float* __restrict__ el,
                                                   float* __restrict__ er, int M) {
  __shared__ __align__(16) ushort As[2 * BM * BK];
  __shared__ __align__(16) ushort Bs[2 * BN * BK];
  const int K = 256, N = 256;
  int bn = blockIdx.x * BN;   // 2 bn-blocks sharing an A tile are adjacent in dispatch
  int bm = blockIdx.y * BM;
  int tid = threadIdx.x;
  int lane = tid & 63, wid = tid >> 6;   // wid 0..7
  int wr = wid >> 1;                     // 0..3 : 32-row strip
  int wc = wid & 1;                      // 0..1 : 64-col strip (one head)

  f32x4 acc[2][4];
#pragma unroll
  for (int mi = 0; mi < 2; ++mi)
#pragma unroll
    for (int ni = 0; ni < 4; ++ni) acc[mi][ni] = (f32x4){0.f, 0.f, 0.f, 0.f};

  // staging: 512 threads x 16B = 4096 elems/issue = 64 rows; 2 issues per operand.
  // lane's row r = i*64 + wid*8 + (lane>>3); slot = lane&7; source col pre-swizzled by r&7.
  auto stage = [&](int kt, int buf) {
#pragma unroll
    for (int i = 0; i < 2; ++i) {
      int r = i * 64 + (tid >> 3);
      int cs = (((tid & 7) ^ (r & 7)) << 3);
      int gr = bm + r;
      if (gr >= M) gr = M - 1;  // clamp; those rows' outputs are discarded
      gl_lds16(A + (size_t)gr * K + kt + cs, As + buf * 8192 + i * 4096 + wid * 512);
      gl_lds16(Bt + (size_t)(bn + r) * K + kt + cs, Bs + buf * 8192 + i * 4096 + wid * 512);
    }
  };

  stage(0, 0);
  asm volatile("s_waitcnt vmcnt(0)" ::: "memory");
  __builtin_amdgcn_s_barrier();

  int swz = (lane & 7) << 3;  // r&7 of every fragment row == lane&7
#pragma unroll
  for (int t = 0; t < 4; ++t) {
    int cur = t & 1;
    if (t < 3) stage((t + 1) * BK, cur ^ 1);
    const ushort* Ab = As + cur * 8192;
    const ushort* Bb = Bs + cur * 8192;
#pragma unroll
    for (int s = 0; s < 2; ++s) {
      bf16x8 af[2], bfr[4];
      int cc = s * 32 + (lane >> 4) * 8;
      int cs = cc ^ swz;
#pragma unroll
      for (int mi = 0; mi < 2; ++mi) {
        int r = wr * 32 + mi * 16 + (lane & 15);
        af[mi] = *(const bf16x8*)(Ab + r * BK + cs);
      }
#pragma unroll
      for (int ni = 0; ni < 4; ++ni) {
        int r = wc * 64 + ni * 16 + (lane & 15);
        bfr[ni] = *(const bf16x8*)(Bb + r * BK + cs);
      }
#pragma unroll
      for (int mi = 0; mi < 2; ++mi)
#pragma unroll
        for (int ni = 0; ni < 4; ++ni)
          acc[mi][ni] = __builtin_amdgcn_mfma_f32_16x16x32_bf16(af[mi], bfr[ni], acc[mi][ni], 0, 0, 0);
    }
    if (t < 3) {
      asm volatile("s_waitcnt vmcnt(0)" ::: "memory");
      __builtin_amdgcn_s_barrier();
    }
  }

  // C store (bf16)
#pragma unroll
  for (int mi = 0; mi < 2; ++mi) {
#pragma unroll
    for (int j = 0; j < 4; ++j) {
      int gr = bm + wr * 32 + mi * 16 + (lane >> 4) * 4 + j;
      if (gr < M) {
#pragma unroll
        for (int ni = 0; ni < 4; ++ni) {
          int gc = bn + wc * 64 + ni * 16 + (lane & 15);
          C[(size_t)gr * N + gc] = f2bf(acc[mi][ni][j]);
        }
      }
    }
  }

  // fused el/er: this wave's 64 cols == head h
  int h = (bn >> 6) + wc;
  float alv[4], arv[4];
#pragma unroll
  for (int ni = 0; ni < 4; ++ni) {
    int d = ni * 16 + (lane & 15);
    alv[ni] = al[h * 64 + d];
    arv[ni] = ar[h * 64 + d];
  }
#pragma unroll
  for (int mi = 0; mi < 2; ++mi) {
#pragma unroll
    for (int j = 0; j < 4; ++j) {
      float pel = acc[mi][0][j] * alv[0] + acc[mi][1][j] * alv[1] +
                  acc[mi][2][j] * alv[2] + acc[mi][3][j] * alv[3];
      float per = acc[mi][0][j] * arv[0] + acc[mi][1][j] * arv[1] +
                  acc[mi][2][j] * arv[2] + acc[mi][3][j] * arv[3];
#pragma unroll
      for (int off = 8; off >= 1; off >>= 1) {
        pel += __shfl_xor(pel, off);
        per += __shfl_xor(per, off);
      }
      int gr = bm + wr * 32 + mi * 16 + (lane >> 4) * 4 + j;
      if ((lane & 15) == 0 && gr < M) {
        el[(size_t)gr * 4 + h] = pel;
        er[(size_t)gr * 4 + h] = per;
      }
    }
  }
}

// ------- fused edge-softmax + aggregation -------
// one wave per dst node; head h = lane>>4, sub = lane&15; lane owns dims 4*lane..4*lane+3
#define CAP 128

__global__ __launch_bounds__(256) void k_agg(const ushort* __restrict__ feat,
                                             const float* __restrict__ el,
                                             const float* __restrict__ er,
                                             const int* __restrict__ rowptr,
                                             const int* __restrict__ esrc,
                                             const float* __restrict__ resid_f32,
                                             const ushort* __restrict__ resid_bf16,
                                             float* __restrict__ out_f32,
                                             ushort* __restrict__ out_bf16, int N) {
  __shared__ float lw[4][CAP * 4];
  int wv = threadIdx.x >> 6;
  int lane = threadIdx.x & 63;
  int n = blockIdx.x * 4 + wv;
  if (n >= N) return;
  int e0 = rowptr[n], e1 = rowptr[n + 1];
  int deg = e1 - e0;
  int h = lane >> 4, sub = lane & 15;
  float ern = er[(size_t)n * 4 + h];
  const ushort* fb = feat + (size_t)lane * 4;

  float a0 = 0.f, a1 = 0.f, a2 = 0.f, a3 = 0.f;
  float inv;

  if (deg <= 16) {
    // ---- register fast path (avg deg = 8): no LDS, no esrc re-read ----
    int s_reg = 0;
    float v = -1e30f;
    if (sub < deg) {
      s_reg = esrc[e0 + sub];
      v = el[(size_t)s_reg * 4 + h] + ern;
      v = v >= 0.f ? v : 0.2f * v;
    }
    float m = v;
    m = fmaxf(m, __shfl_xor(m, 1));
    m = fmaxf(m, __shfl_xor(m, 2));
    m = fmaxf(m, __shfl_xor(m, 4));
    m = fmaxf(m, __shfl_xor(m, 8));
    float w_reg = (sub < deg) ? __expf(v - m) : 0.f;
    float den = w_reg;
    den += __shfl_xor(den, 1);
    den += __shfl_xor(den, 2);
    den += __shfl_xor(den, 4);
    den += __shfl_xor(den, 8);
    inv = 1.f / fmaxf(den, 1e-9f);
    int hb = h << 4;
    int j = 0;
    for (; j + 4 <= deg; j += 4) {
      int s0 = __shfl(s_reg, j), s1 = __shfl(s_reg, j + 1);
      int s2 = __shfl(s_reg, j + 2), s3 = __shfl(s_reg, j + 3);
      uint2 f0 = *(const uint2*)(fb + (size_t)s0 * 256);
      uint2 f1 = *(const uint2*)(fb + (size_t)s1 * 256);
      uint2 f2 = *(const uint2*)(fb + (size_t)s2 * 256);
      uint2 f3 = *(const uint2*)(fb + (size_t)s3 * 256);
      float w0 = __shfl(w_reg, hb + j), w1 = __shfl(w_reg, hb + j + 1);
      float w2 = __shfl(w_reg, hb + j + 2), w3 = __shfl(w_reg, hb + j + 3);
      a0 += w0 * bflo(f0.x); a1 += w0 * bfhi(f0.x); a2 += w0 * bflo(f0.y); a3 += w0 * bfhi(f0.y);
      a0 += w1 * bflo(f1.x); a1 += w1 * bfhi(f1.x); a2 += w1 * bflo(f1.y); a3 += w1 * bfhi(f1.y);
      a0 += w2 * bflo(f2.x); a1 += w2 * bfhi(f2.x); a2 += w2 * bflo(f2.y); a3 += w2 * bfhi(f2.y);
      a0 += w3 * bflo(f3.x); a1 += w3 * bfhi(f3.x); a2 += w3 * bflo(f3.y); a3 += w3 * bfhi(f3.y);
    }
    for (; j < deg; ++j) {
      int sj = __shfl(s_reg, j);
      uint2 f = *(const uint2*)(fb + (size_t)sj * 256);
      float wj = __shfl(w_reg, hb + j);
      a0 += wj * bflo(f.x); a1 += wj * bfhi(f.x); a2 += wj * bflo(f.y); a3 += wj * bfhi(f.y);
    }
  } else {
    // ---- LDS path (deg > 16), with >CAP fallback ----
    float* lwp = lw[wv];
    float m = -1e30f;
    for (int jj = sub; jj < deg; jj += 16) {
      int s = esrc[e0 + jj];
      float v = el[(size_t)s * 4 + h] + ern;
      v = v >= 0.f ? v : 0.2f * v;
      if (jj < CAP) lwp[jj * 4 + h] = v;
      m = fmaxf(m, v);
    }
    m = fmaxf(m, __shfl_xor(m, 1));
    m = fmaxf(m, __shfl_xor(m, 2));
    m = fmaxf(m, __shfl_xor(m, 4));
    m = fmaxf(m, __shfl_xor(m, 8));
    float den = 0.f;
    for (int jj = sub; jj < deg; jj += 16) {
      float v;
      if (jj < CAP) {
        v = lwp[jj * 4 + h];
      } else {
        int s = esrc[e0 + jj];
        v = el[(size_t)s * 4 + h] + ern;
        v = v >= 0.f ? v : 0.2f * v;
      }
      float w = __expf(v - m);
      if (jj < CAP) lwp[jj * 4 + h] = w;
      den += w;
    }
    den += __shfl_xor(den, 1);
    den += __shfl_xor(den, 2);
    den += __shfl_xor(den, 4);
    den += __shfl_xor(den, 8);
    inv = 1.f / fmaxf(den, 1e-9f);

    if (deg <= CAP) {
      int j = 0;
      for (; j + 8 <= deg; j += 8) {
        int s[8];
        uint2 f[8];
        float w[8];
#pragma unroll
        for (int t = 0; t < 8; ++t) s[t] = esrc[e0 + j + t];
#pragma unroll
        for (int t = 0; t < 8; ++t) f[t] = *(const uint2*)(fb + (size_t)s[t] * 256);
#pragma unroll
        for (int t = 0; t < 8; ++t) w[t] = lwp[(j + t) * 4 + h];
#pragma unroll
        for (int t = 0; t < 8; ++t) {
          a0 += w[t] * bflo(f[t].x); a1 += w[t] * bfhi(f[t].x);
          a2 += w[t] * bflo(f[t].y); a3 += w[t] * bfhi(f[t].y);
        }
      }
      for (; j < deg; ++j) {
        int s = esrc[e0 + j];
        uint2 f = *(const uint2*)(fb + (size_t)s * 256);
        float w = lwp[j * 4 + h];
        a0 += w * bflo(f.x); a1 += w * bfhi(f.x); a2 += w * bflo(f.y); a3 += w * bfhi(f.y);
      }
    } else {
      for (int j = 0; j < deg; ++j) {
        int s = esrc[e0 + j];
        float w;
        if (j < CAP) {
          w = lwp[j * 4 + h];
        } else {
          float v = el[(size_t)s * 4 + h] + ern;
          v = v >= 0.f ? v : 0.2f * v;
          w = __expf(v - m);
        }
        uint2 f = *(const uint2*)(fb + (size_t)s * 256);
        a0 += w * bflo(f.x); a1 += w * bfhi(f.x); a2 += w * bflo(f.y); a3 += w * bfhi(f.y);
      }
    }
  }

  float o0 = a0 * inv, o1 = a1 * inv, o2 = a2 * inv, o3 = a3 * inv;
  size_t base = (size_t)n * 256 + lane * 4;
  if (resid_f32) {
    float4 r = *(const float4*)(resid_f32 + base);
    o0 += r.x; o1 += r.y; o2 += r.z; o3 += r.w;
  } else if (resid_bf16) {
    uint2 r = *(const uint2*)(resid_bf16 + base);
    o0 += bflo(r.x); o1 += bfhi(r.x); o2 += bflo(r.y); o3 += bfhi(r.y);
  }
  o0 = fmaxf(o0, 0.f); o1 = fmaxf(o1, 0.f); o2 = fmaxf(o2, 0.f); o3 = fmaxf(o3, 0.f);
  if (out_f32) {
    float4 o = {o0, o1, o2, o3};
    *(float4*)(out_f32 + base) = o;
  }
  if (out_bf16) {
    uint2 p;
    p.x = (uint)f2bf(o0) | ((uint)f2bf(o1) << 16);
    p.y = (uint)f2bf(o2) | ((uint)f2bf(o3) << 16);
    *(uint2*)(out_bf16 + base) = p;
  }
}

extern "C" void kernel_launch(void* const* d_in, const int* in_sizes, int n_in,
                              void* d_out, int out_size, void* d_ws, size_t ws_size,
                              hipStream_t stream) {
  const float* x = (const float*)d_in[0];
  const int* src = (const int*)d_in[1];
  const int* dst = (const int*)d_in[2];
  const float* W[3]  = {(const float*)d_in[3], (const float*)d_in[6], (const float*)d_in[9]};
  const float* al[3] = {(const float*)d_in[4], (const float*)d_in[7], (const float*)d_in[10]};
  const float* ar[3] = {(const float*)d_in[5], (const float*)d_in[8], (const float*)d_in[11]};
  const int N = in_sizes[0] / 256;
  const int E = in_sizes[1];
  float* out = (float*)d_out;

  char* ws = (char*)d_ws;
  size_t off = 0;
  auto alloc = [&](size_t bytes) -> void* {
    void* p = ws + off;
    off += (bytes + 255) & ~(size_t)255;
    return p;
  };
  ushort* xb    = (ushort*)alloc((size_t)N * 256 * 2);
  ushort* h1b   = (ushort*)alloc((size_t)N * 256 * 2);
  ushort* h2b   = (ushort*)alloc((size_t)N * 256 * 2);
  ushort* featb = (ushort*)alloc((size_t)N * 256 * 2);
  float*  el    = (float*)alloc((size_t)N * 4 * 4);
  float*  er    = (float*)alloc((size_t)N * 4 * 4);
  ushort* Wt[3];
  for (int i = 0; i < 3; ++i) Wt[i] = (ushort*)alloc(256 * 256 * 2);
  int* cntfill = (int*)alloc((size_t)N * 2 * 4);  // cnt + fill, ONE block: memset covers both
  int* cnt  = cntfill;
  int* fill = cntfill + N;
  int* rowptr = (int*)alloc((size_t)(N + 1) * 4);
  int* esrc   = (int*)alloc((size_t)E * 4);
  int* bsum   = (int*)alloc(4096);

  long totx = (long)N * 256;
  int G = (N + 1023) / 1024;
  k_cast_bf16<<<(int)((totx / 8 + 255) / 256), 256, 0, stream>>>(x, xb, totx);
  k_transpose3<<<dim3(4, 4, 3), 256, 0, stream>>>(W[0], W[1], W[2], Wt[0], Wt[1], Wt[2]);
  hipMemsetAsync(cntfill, 0, (size_t)N * 2 * 4, stream);
  k_count<<<(E + 255) / 256, 256, 0, stream>>>(dst, cnt, E);
  k_scan1<<<G, 1024, 0, stream>>>(cnt, rowptr, bsum, N);
  k_scan2<<<1, 64, 0, stream>>>(bsum, G);
  k_scan3<<<G, 1024, 0, stream>>>(rowptr, bsum, N);
  k_scatter<<<(E + 255) / 256, 256, 0, stream>>>(dst, src, rowptr, fill, esrc, E);

  dim3 ggrid(2, (N + BM - 1) / BM);   // bn fast: A-tile reuse in L2
  dim3 agrid((N + 3) / 4);

  // layer 0: residual = x (f32); output: h1b (bf16)
  k_gemm_bf16<<<ggrid, 512, 0, stream>>>(xb, Wt[0], al[0], ar[0], featb, el, er, N);
  k_agg<<<agrid, 256, 0, stream>>>(featb, el, er, rowptr, esrc, x, nullptr, nullptr, h1b, N);

  // layer 1: residual = h1b (bf16); output: h2b (bf16)
  k_gemm_bf16<<<ggrid, 512, 0, stream>>>(h1b, Wt[1], al[1], ar[1], featb, el, er, N);
  k_agg<<<agrid, 256, 0, stream>>>(featb, el, er, rowptr, esrc, nullptr, h1b, nullptr, h2b, N);

  // layer 2: no residual; output: d_out (f32)
  k_gemm_bf16<<<ggrid, 512, 0, stream>>>(h2b, Wt[2], al[2], ar[2], featb, el, er, N);
  k_agg<<<agrid, 256, 0, stream>>>(featb, el, er, rowptr, esrc, nullptr, nullptr, out, nullptr, N);
}